// Round 18
// baseline (1245.214 us; speedup 1.0000x reference)
//
#include <hip/hip_runtime.h>
#include <hip/hip_bf16.h>
#include <math.h>

#define B_   32
#define S_   2688
#define D_   128
#define DI_  256
#define DS_  16
#define NROWS (B_*S_)   // 86016

typedef __hip_bfloat16 bf16;
typedef float f32x4 __attribute__((ext_vector_type(4)));
typedef float f32x2 __attribute__((ext_vector_type(2)));
typedef short bf16x8 __attribute__((ext_vector_type(8)));
#define MFMA16(a,b,c) __builtin_amdgcn_mfma_f32_16x16x32_bf16(a,b,c,0,0,0)

__device__ __forceinline__ float bf2f(bf16 v){ return __bfloat162float(v); }
__device__ __forceinline__ bf16  f2bf(float f){ return __float2bfloat16(f); }
__device__ __forceinline__ float uphalf(unsigned short u){
  union { unsigned int i; float f; } c; c.i = ((unsigned int)u) << 16; return c.f;
}
__device__ __forceinline__ unsigned int pk2(float a, float b){
  unsigned int lo = __hip_bfloat16_raw(f2bf(a)).x;
  unsigned int hi = __hip_bfloat16_raw(f2bf(b)).x;
  return lo | (hi << 16);
}

// log(n+1) fp32 constants for the A_log pattern check.
__device__ __constant__ float LOGN[16] = {
  0.0f, 0.69314718056f, 1.09861228867f, 1.38629436112f,
  1.60943791243f, 1.79175946923f, 1.94591014906f, 2.07944154168f,
  2.19722457734f, 2.30258509299f, 2.39789527280f, 2.48490664979f,
  2.56494935746f, 2.63905732962f, 2.70805020110f, 2.77258872224f };

// dA2[i] = {exp(dt*A_{2i}), exp(dt*A_{2i+1})}.
// Fast path (ok): A_n = -(n+1) => dA = w^(n+1), w=exp(-dt); packed chain *w^2.
__device__ __forceinline__ void comp_dA2(f32x2 dA2[8], float dtv, bool ok,
                                         const f32x2 anl2[8]){
  if (ok){
    float w1 = __expf(-dtv);
    float w2 = w1*w1;
    f32x2 ww; ww.x = w2; ww.y = w2;
    dA2[0].x = w1; dA2[0].y = w2;
    #pragma unroll
    for (int i=1;i<8;i++) dA2[i] = dA2[i-1]*ww;
  } else {
    #pragma unroll
    for (int i=0;i<8;i++){
      dA2[i].x = exp2f(dtv*anl2[i].x);
      dA2[i].y = exp2f(dtv*anl2[i].y);
    }
  }
}

// ---------------- init: x = concat(feat0, feat1) along seq ----------------
__global__ void k_init_x(const float* __restrict__ f0, const float* __restrict__ f1,
                         float* __restrict__ x){
  int idx = blockIdx.x*256 + threadIdx.x;
  if (idx >= B_*S_*D_) return;
  const int per_b = S_*D_;
  const int half  = 1344*D_;
  int b = idx / per_b;
  int rem = idx - b*per_b;
  x[idx] = (rem < half) ? f0[b*half + rem] : f1[b*half + rem - half];
}

// -------- weight convert/transpose to bf16 ---------------------------------
__global__ void k_wconv(const float* __restrict__ W_in, const float* __restrict__ Wx,
                        const float* __restrict__ W_out,
                        bf16* __restrict__ Wt_in, bf16* __restrict__ Wxt,
                        bf16* __restrict__ Wt_out){
  int idx = blockIdx.x*256 + threadIdx.x;   // 1728*256 = 442368
  if (idx < 262144){
    int k = idx & 127, n = (idx>>7) & 511, lr = idx>>16;
    Wt_in[idx] = f2bf(W_in[((size_t)lr*128 + k)*512 + n]);
    return;
  }
  int i2 = idx - 262144;
  if (i2 < 131072){
    int k = i2 & 255, n = (i2>>8) & 127, lr = i2>>15;
    Wt_out[i2] = f2bf(W_out[((size_t)lr*256 + k)*128 + n]);
    return;
  }
  int i3 = i2 - 131072;
  if (i3 < 49152){
    int k = i3 & 255, nn = i3>>8, n = nn % 48, lr = nn / 48;
    Wxt[i3] = (n < 40) ? f2bf(Wx[((size_t)lr*256 + k)*40 + n]) : f2bf(0.f);
  }
}

// ------------- gemm_in (MFMA): [xi|z] = x(_rev) @ W_in ---------------------
__global__ __launch_bounds__(256) void k_gemm_in_mfma(const float* __restrict__ x,
      const bf16* __restrict__ Wt, bf16* __restrict__ xi, bf16* __restrict__ z, int rev){
  __shared__ __align__(16) unsigned short a_sh[64][136];
  __shared__ __align__(16) unsigned short b_sh[64][136];
  const int r0 = blockIdx.x*64;              // 1344 blocks
  const int b  = r0 / S_;
  const int t0 = r0 - b*S_;
  const int tid = threadIdx.x;
  const int lane = tid & 63, wv = tid >> 6;
  const int wr = (wv>>1)*32, wc = (wv&1)*32;
  const int fr = lane & 15, fk = (lane>>4)*8;

  #pragma unroll
  for (int q=0;q<4;q++){
    int fid = tid + 256*q;
    int r = fid >> 4, g = fid & 15;
    int t = t0 + r;
    int rg = b*S_ + (rev ? (S_-1 - t) : t);
    const float* src = x + (size_t)rg*128 + g*8;
    float4 v0 = *(const float4*)(src);
    float4 v1 = *(const float4*)(src + 4);
    uint4 pk;
    pk.x = pk2(v0.x, v0.y);
    pk.y = pk2(v0.z, v0.w);
    pk.z = pk2(v1.x, v1.y);
    pk.w = pk2(v1.z, v1.w);
    *(uint4*)&a_sh[r][g*8] = pk;
    *(uint4*)&b_sh[r][g*8] = *(const uint4*)(Wt + (size_t)r*128 + g*8);
  }
  __syncthreads();

  for (int bn=0;bn<8;bn++){
    if (bn){
      __syncthreads();
      #pragma unroll
      for (int q=0;q<4;q++){
        int fid = tid + 256*q;
        int r = fid >> 4, g = fid & 15;
        *(uint4*)&b_sh[r][g*8] = *(const uint4*)(Wt + (size_t)(bn*64+r)*128 + g*8);
      }
      __syncthreads();
    }
    const f32x4 zero = {0.f,0.f,0.f,0.f};
    f32x4 acc[2][2] = {{zero,zero},{zero,zero}};
    #pragma unroll
    for (int ks=0;ks<4;ks++){
      bf16x8 a0 = *(const bf16x8*)&a_sh[wr+fr   ][ks*32+fk];
      bf16x8 a1 = *(const bf16x8*)&a_sh[wr+16+fr][ks*32+fk];
      bf16x8 b0 = *(const bf16x8*)&b_sh[wc+fr   ][ks*32+fk];
      bf16x8 b1 = *(const bf16x8*)&b_sh[wc+16+fr][ks*32+fk];
      acc[0][0] = MFMA16(a0,b0,acc[0][0]);
      acc[0][1] = MFMA16(a0,b1,acc[0][1]);
      acc[1][0] = MFMA16(a1,b0,acc[1][0]);
      acc[1][1] = MFMA16(a1,b1,acc[1][1]);
    }
    #pragma unroll
    for (int fi=0;fi<2;fi++){
      #pragma unroll
      for (int fj=0;fj<2;fj++){
        int gcol = bn*64 + wc + fj*16 + fr;
        bf16* dst = (gcol < 256) ? xi : z;
        int cc = gcol & 255;
        #pragma unroll
        for (int r=0;r<4;r++){
          size_t row = (size_t)(r0 + wr + fi*16 + (lane>>4)*4 + r);
          dst[row*256 + cc] = f2bf(acc[fi][fj][r]);
        }
      }
    }
  }
}

// ------- conv + silu (vectorized: 4 rows x 8 channels per thread) ----------
__global__ __launch_bounds__(256) void k_conv_silu(const bf16* __restrict__ xi,
      const float* __restrict__ cw, const float* __restrict__ cb,
      bf16* __restrict__ xc){
  int gid = blockIdx.x*256 + threadIdx.x;
  int dg  = gid & 31;
  int rg  = gid >> 5;
  const int r0 = rg*4;
  const int t0 = r0 % S_;
  const int d0 = dg*8;

  uint4 w[7];
  const uint4 z4 = make_uint4(0,0,0,0);
  #pragma unroll
  for (int i=0;i<7;i++){
    int off = i - 3;
    if (t0 == 0 && i < 3) w[i] = z4;
    else w[i] = *(const uint4*)(xi + (size_t)(r0+off)*256 + d0);
  }
  float f[7][8];
  #pragma unroll
  for (int i=0;i<7;i++){
    unsigned int ww[4] = {w[i].x, w[i].y, w[i].z, w[i].w};
    #pragma unroll
    for (int p=0;p<4;p++){
      f[i][p*2+0] = uphalf((unsigned short)(ww[p] & 0xffffu));
      f[i][p*2+1] = uphalf((unsigned short)(ww[p] >> 16));
    }
  }
  float wt[8][4], bias[8];
  #pragma unroll
  for (int c2=0;c2<2;c2++){
    float4 b4 = *(const float4*)(cb + d0 + c2*4);
    bias[c2*4+0]=b4.x; bias[c2*4+1]=b4.y; bias[c2*4+2]=b4.z; bias[c2*4+3]=b4.w;
  }
  #pragma unroll
  for (int c=0;c<8;c++){
    float4 w4 = *(const float4*)(cw + (d0+c)*4);
    wt[c][0]=w4.x; wt[c][1]=w4.y; wt[c][2]=w4.z; wt[c][3]=w4.w;
  }
  #pragma unroll
  for (int k=0;k<4;k++){
    unsigned int owords[4];
    #pragma unroll
    for (int p=0;p<4;p++){
      float o2[2];
      #pragma unroll
      for (int h=0;h<2;h++){
        int c = p*2+h;
        float acc = bias[c];
        #pragma unroll
        for (int j=0;j<4;j++) acc = fmaf(wt[c][j], f[k+j][c], acc);
        float sig = 1.f/(1.f + __expf(-acc));
        o2[h] = acc*sig;
      }
      owords[p] = pk2(o2[0], o2[1]);
    }
    uint4 outv = make_uint4(owords[0],owords[1],owords[2],owords[3]);
    *(uint4*)(xc + (size_t)(r0+k)*256 + d0) = outv;
  }
}

// -- gemm_x+dt (MFMA): xdbl = xc@Wx; BC[row][32]=B|C; dtb=softplus(dbl@Wdt+b)
__global__ __launch_bounds__(256) void k_gemm_x_dt_mfma(const bf16* __restrict__ xc,
      const bf16* __restrict__ Wxt, const float* __restrict__ Wdt, const float* __restrict__ bdt,
      float* __restrict__ BC, bf16* __restrict__ dtb){
  __shared__ __align__(16) unsigned short a_sh[64][136];
  __shared__ __align__(16) unsigned short b_sh[48][136];
  __shared__ __align__(16) float s_dbl[64][8];
  const int r0 = blockIdx.x*64;              // 1344 blocks
  const int tid = threadIdx.x;
  const int lane = tid & 63, wv = tid >> 6;
  const int fr = lane & 15, fk = (lane>>4)*8;
  const f32x4 zero = {0.f,0.f,0.f,0.f};
  f32x4 acc[3] = {zero,zero,zero};

  for (int kst=0;kst<2;kst++){
    if (kst) __syncthreads();
    #pragma unroll
    for (int q=0;q<4;q++){
      int fid = tid + 256*q;
      int r = fid >> 4, g = fid & 15;
      *(uint4*)&a_sh[r][g*8] = *(const uint4*)(xc + (size_t)(r0+r)*256 + kst*128 + g*8);
      if (fid < 768)
        *(uint4*)&b_sh[r][g*8] = *(const uint4*)(Wxt + (size_t)r*256 + kst*128 + g*8);
    }
    __syncthreads();
    #pragma unroll
    for (int ks=0;ks<4;ks++){
      bf16x8 a0 = *(const bf16x8*)&a_sh[wv*16+fr][ks*32+fk];
      #pragma unroll
      for (int fj=0;fj<3;fj++){
        bf16x8 bb = *(const bf16x8*)&b_sh[fj*16+fr][ks*32+fk];
        acc[fj] = MFMA16(a0,bb,acc[fj]);
      }
    }
  }
  #pragma unroll
  for (int fj=0;fj<3;fj++){
    int col = fj*16 + fr;
    #pragma unroll
    for (int r=0;r<4;r++){
      int rr = wv*16 + (lane>>4)*4 + r;
      size_t row = (size_t)(r0 + rr);
      if (col < 8)       s_dbl[rr][col] = acc[fj][r];
      else if (col < 40) BC[row*32 + (col-8)] = acc[fj][r];
    }
  }
  __syncthreads();
  float wdt[8];
  #pragma unroll
  for (int j=0;j<8;j++) wdt[j] = Wdt[j*256 + tid];
  float bd = bdt[tid];
  #pragma unroll
  for (int r=0;r<64;r++){
    float4 d0 = *(const float4*)&s_dbl[r][0];
    float4 d1 = *(const float4*)&s_dbl[r][4];
    float v = bd;
    v = fmaf(d0.x, wdt[0], v);
    v = fmaf(d0.y, wdt[1], v);
    v = fmaf(d0.z, wdt[2], v);
    v = fmaf(d0.w, wdt[3], v);
    v = fmaf(d1.x, wdt[4], v);
    v = fmaf(d1.y, wdt[5], v);
    v = fmaf(d1.z, wdt[6], v);
    v = fmaf(d1.w, wdt[7], v);
    float sp = (v > 20.f) ? v : __logf(1.f + __expf(v));
    dtb[(size_t)(r0+r)*256 + tid] = f2bf(sp);
  }
}

// ==== chunked scan (2 channels/thread, 2 chunks/block, packed fp32) =========
__device__ __forceinline__ bool load_A(const float* Alog, int d, f32x2 anl2[8]){
  const float4* ap = (const float4*)(Alog + d*16);
  float4 a0=ap[0], a1=ap[1], a2=ap[2], a3=ap[3];
  float tmp[16] = {a0.x,a0.y,a0.z,a0.w, a1.x,a1.y,a1.z,a1.w,
                   a2.x,a2.y,a2.z,a2.w, a3.x,a3.y,a3.z,a3.w};
  bool ok = true;
  #pragma unroll
  for (int n=0;n<16;n++) ok = ok && (fabsf(tmp[n] - LOGN[n]) < 1e-4f);
  if (!ok){
    #pragma unroll
    for (int i=0;i<8;i++){
      anl2[i].x = -__expf(tmp[i*2+0]) * 1.44269504f;
      anl2[i].y = -__expf(tmp[i*2+1]) * 1.44269504f;
    }
  }
  return ok;
}

__device__ __forceinline__ void unpackBC(const float4 v[4], f32x2 o[8]){
  o[0].x=v[0].x; o[0].y=v[0].y;  o[1].x=v[0].z; o[1].y=v[0].w;
  o[2].x=v[1].x; o[2].y=v[1].y;  o[3].x=v[1].z; o[3].y=v[1].w;
  o[4].x=v[2].x; o[4].y=v[2].y;  o[5].x=v[2].z; o[5].y=v[2].w;
  o[6].x=v[3].x; o[6].y=v[3].y;  o[7].x=v[3].z; o[7].y=v[3].w;
}

template<int CL>
__global__ __launch_bounds__(256) void k_scan_p1(const bf16* __restrict__ xc,
      const bf16* __restrict__ dtb, const float* __restrict__ BC,
      const float* __restrict__ Alog,
      float* __restrict__ hend, float* __restrict__ sumdt, int nc, int cl_rt){
  const int ncH = (nc+1) >> 1;
  const int b = blockIdx.x / ncH;
  const int cp = blockIdx.x - b*ncH;
  const int c = cp*2 + (threadIdx.x >> 7);
  if (c >= nc) return;
  const int d0 = (threadIdx.x & 127)*2;
  const int cl = CL ? CL : cl_rt;
  const size_t idx = (size_t)b*nc + c;
  f32x2 anlA[8], anlB[8];
  const bool okA = load_A(Alog, d0,   anlA);
  const bool okB = load_A(Alog, d0+1, anlB);
  f32x2 hA[8], hB[8];
  #pragma unroll
  for (int i=0;i<8;i++){ hA[i].x=0.f; hA[i].y=0.f; hB[i].x=0.f; hB[i].y=0.f; }
  float sA = 0.f, sB = 0.f;
  const size_t rowbase = (size_t)b*S_ + (size_t)c*cl;
  #pragma unroll 2
  for (int t=0;t<cl;t++){
    size_t row = rowbase + t;
    unsigned int dtp = *(const unsigned int*)(dtb + row*256 + d0);
    unsigned int up  = *(const unsigned int*)(xc  + row*256 + d0);
    float dtA = uphalf((unsigned short)(dtp & 0xffffu));
    float dtB = uphalf((unsigned short)(dtp >> 16));
    float uA  = uphalf((unsigned short)(up  & 0xffffu));
    float uB  = uphalf((unsigned short)(up  >> 16));
    sA += dtA; sB += dtB;
    const float4* bp = (const float4*)(BC + row*32);
    float4 Bv[4] = {bp[0], bp[1], bp[2], bp[3]};
    f32x2 B2[8];
    unpackBC(Bv, B2);
    f32x2 duA; duA.x = dtA*uA; duA.y = dtA*uA;
    f32x2 duB; duB.x = dtB*uB; duB.y = dtB*uB;
    f32x2 dAA[8], dAB[8];
    comp_dA2(dAA, dtA, okA, anlA);
    comp_dA2(dAB, dtB, okB, anlB);
    #pragma unroll
    for (int i=0;i<8;i++){
      hA[i] = dAA[i]*hA[i] + duA*B2[i];
      hB[i] = dAB[i]*hB[i] + duB*B2[i];
    }
  }
  float4* hp = (float4*)(hend + (idx*256 + d0)*16);
  hp[0] = make_float4(hA[0].x,hA[0].y,hA[1].x,hA[1].y);
  hp[1] = make_float4(hA[2].x,hA[2].y,hA[3].x,hA[3].y);
  hp[2] = make_float4(hA[4].x,hA[4].y,hA[5].x,hA[5].y);
  hp[3] = make_float4(hA[6].x,hA[6].y,hA[7].x,hA[7].y);
  hp[4] = make_float4(hB[0].x,hB[0].y,hB[1].x,hB[1].y);
  hp[5] = make_float4(hB[2].x,hB[2].y,hB[3].x,hB[3].y);
  hp[6] = make_float4(hB[4].x,hB[4].y,hB[5].x,hB[5].y);
  hp[7] = make_float4(hB[6].x,hB[6].y,hB[7].x,hB[7].y);
  *(float2*)(sumdt + idx*256 + d0) = make_float2(sA, sB);
}

// --- combine: one (b,d,n) scalar chain per thread; 512 blocks --------------
__global__ __launch_bounds__(256) void k_scan_comb(const float* __restrict__ Alog,
      const float* __restrict__ sumdt, float* __restrict__ hend, int nc){
  const int blk = blockIdx.x;
  const int b  = blk >> 4;
  const int dg = blk & 15;
  const int tid = threadIdx.x;
  const int dl = tid >> 4;
  const int n  = tid & 15;
  const int d  = dg*16 + dl;
  const float anl2 = -__expf(Alog[d*16 + n]) * 1.44269504f;
  float carry = 0.f;
  const size_t basei = (size_t)b*nc;
  for (int c=0;c<nc;c++){
    size_t blkc = basei + c;
    size_t hidx = (blkc*256 + d)*16 + n;
    float he  = hend[hidx];
    float sdt = sumdt[blkc*256 + d];
    hend[hidx] = carry;
    carry = fmaf(exp2f(sdt*anl2), carry, he);
  }
}

template<int CL>
__global__ __launch_bounds__(256) void k_scan_p2(const bf16* __restrict__ xcin,
      const bf16* __restrict__ dtb, const float* __restrict__ BC,
      const bf16* __restrict__ zb, const float* __restrict__ Alog,
      const float* __restrict__ Dpar, const float* __restrict__ hend,
      bf16* __restrict__ ym, int nc, int cl_rt){
  const int ncH = (nc+1) >> 1;
  const int b = blockIdx.x / ncH;
  const int cp = blockIdx.x - b*ncH;
  const int c = cp*2 + (threadIdx.x >> 7);
  if (c >= nc) return;
  const int d0 = (threadIdx.x & 127)*2;
  const int cl = CL ? CL : cl_rt;
  const size_t idx = (size_t)b*nc + c;
  f32x2 anlA[8], anlB[8];
  const bool okA = load_A(Alog, d0,   anlA);
  const bool okB = load_A(Alog, d0+1, anlB);
  float2 Dp2 = *(const float2*)(Dpar + d0);
  f32x2 hA[8], hB[8];
  {
    const float4* hp = (const float4*)(hend + (idx*256 + d0)*16);
    float4 v0=hp[0], v1=hp[1], v2=hp[2], v3=hp[3];
    float4 v4=hp[4], v5=hp[5], v6=hp[6], v7=hp[7];
    hA[0].x=v0.x; hA[0].y=v0.y;  hA[1].x=v0.z; hA[1].y=v0.w;
    hA[2].x=v1.x; hA[2].y=v1.y;  hA[3].x=v1.z; hA[3].y=v1.w;
    hA[4].x=v2.x; hA[4].y=v2.y;  hA[5].x=v2.z; hA[5].y=v2.w;
    hA[6].x=v3.x; hA[6].y=v3.y;  hA[7].x=v3.z; hA[7].y=v3.w;
    hB[0].x=v4.x; hB[0].y=v4.y;  hB[1].x=v4.z; hB[1].y=v4.w;
    hB[2].x=v5.x; hB[2].y=v5.y;  hB[3].x=v5.z; hB[3].y=v5.w;
    hB[4].x=v6.x; hB[4].y=v6.y;  hB[5].x=v6.z; hB[5].y=v6.w;
    hB[6].x=v7.x; hB[6].y=v7.y;  hB[7].x=v7.z; hB[7].y=v7.w;
  }
  const size_t rowbase = (size_t)b*S_ + (size_t)c*cl;
  #pragma unroll 2
  for (int t=0;t<cl;t++){
    size_t row = rowbase + t;
    unsigned int dtp = *(const unsigned int*)(dtb  + row*256 + d0);
    unsigned int up  = *(const unsigned int*)(xcin + row*256 + d0);
    unsigned int zp  = *(const unsigned int*)(zb   + row*256 + d0);
    float dtA = uphalf((unsigned short)(dtp & 0xffffu));
    float dtB = uphalf((unsigned short)(dtp >> 16));
    float uA  = uphalf((unsigned short)(up  & 0xffffu));
    float uB  = uphalf((unsigned short)(up  >> 16));
    const float4* bp = (const float4*)(BC + row*32);
    float4 Bv[4] = {bp[0], bp[1], bp[2], bp[3]};
    float4 Cv[4] = {bp[4], bp[5], bp[6], bp[7]};
    f32x2 B2[8], C2[8];
    unpackBC(Bv, B2);
    unpackBC(Cv, C2);
    f32x2 duA; duA.x = dtA*uA; duA.y = dtA*uA;
    f32x2 duB; duB.x = dtB*uB; duB.y = dtB*uB;
    f32x2 dAA[8], dAB[8];
    comp_dA2(dAA, dtA, okA, anlA);
    comp_dA2(dAB, dtB, okB, anlB);
    f32x2 accA; accA.x=0.f; accA.y=0.f;
    f32x2 accB; accB.x=0.f; accB.y=0.f;
    #pragma unroll
    for (int i=0;i<8;i++){
      hA[i] = dAA[i]*hA[i] + duA*B2[i];
      hB[i] = dAB[i]*hB[i] + duB*B2[i];
      accA = accA + hA[i]*C2[i];
      accB = accB + hB[i]*C2[i];
    }
    float pA = accA.x + accA.y;
    float pB = accB.x + accB.y;
    float yA = fmaf(uA, Dp2.x, pA);
    float yB = fmaf(uB, Dp2.y, pB);
    float zA = uphalf((unsigned short)(zp & 0xffffu));
    float zB = uphalf((unsigned short)(zp >> 16));
    float gA = zA / (1.f + __expf(-zA));
    float gB = zB / (1.f + __expf(-zB));
    *(unsigned int*)(ym + row*256 + d0) = pk2(yA*gA, yB*gB);
  }
}

// ------- gemm_out (MFMA): dx = ym @ W_out (K=256), fwd/bwd-fold ------------
__global__ __launch_bounds__(256) void k_gemm_out_mfma(const bf16* __restrict__ ym,
      const bf16* __restrict__ Wt, bf16* __restrict__ dx, int rev){
  __shared__ __align__(16) unsigned short a_sh[64][136];
  __shared__ __align__(16) unsigned short b_sh[64][136];
  const int blk = blockIdx.x;                // 1344 * 2
  const int bm = blk >> 1, bn = blk & 1;
  const int r0 = bm*64, n0 = bn*64;
  const int b  = r0 / S_;
  const int t0 = r0 - b*S_;
  const int tid = threadIdx.x;
  const int lane = tid & 63, wv = tid >> 6;
  const int wr = (wv>>1)*32, wc = (wv&1)*32;
  const int fr = lane & 15, fk = (lane>>4)*8;
  const f32x4 zero = {0.f,0.f,0.f,0.f};
  f32x4 acc[2][2] = {{zero,zero},{zero,zero}};

  for (int kst=0;kst<2;kst++){
    if (kst) __syncthreads();
    #pragma unroll
    for (int q=0;q<4;q++){
      int fid = tid + 256*q;
      int r = fid >> 4, g = fid & 15;
      *(uint4*)&a_sh[r][g*8] = *(const uint4*)(ym + (size_t)(r0+r)*256 + kst*128 + g*8);
      *(uint4*)&b_sh[r][g*8] = *(const uint4*)(Wt + (size_t)(n0+r)*256 + kst*128 + g*8);
    }
    __syncthreads();
    #pragma unroll
    for (int ks=0;ks<4;ks++){
      bf16x8 a0 = *(const bf16x8*)&a_sh[wr+fr   ][ks*32+fk];
      bf16x8 a1 = *(const bf16x8*)&a_sh[wr+16+fr][ks*32+fk];
      bf16x8 b0 = *(const bf16x8*)&b_sh[wc+fr   ][ks*32+fk];
      bf16x8 b1 = *(const bf16x8*)&b_sh[wc+16+fr][ks*32+fk];
      acc[0][0] = MFMA16(a0,b0,acc[0][0]);
      acc[0][1] = MFMA16(a0,b1,acc[0][1]);
      acc[1][0] = MFMA16(a1,b0,acc[1][0]);
      acc[1][1] = MFMA16(a1,b1,acc[1][1]);
    }
  }
  #pragma unroll
  for (int fi=0;fi<2;fi++){
    #pragma unroll
    for (int fj=0;fj<2;fj++){
      int c = n0 + wc + fj*16 + fr;
      #pragma unroll
      for (int r=0;r<4;r++){
        int t = t0 + wr + fi*16 + (lane>>4)*4 + r;
        size_t drow = (size_t)b*S_ + (rev ? (S_-1 - t) : t);
        if (rev){
          float old = bf2f(dx[drow*128 + c]);
          dx[drow*128 + c] = f2bf(old + 0.5f*acc[fi][fj][r]);
        } else {
          dx[drow*128 + c] = f2bf(0.5f*acc[fi][fj][r]);
        }
      }
    }
  }
}

// --- combine + layernorm + residual (vectorized: 4 ch/lane, 2 rows/wave) ---
__global__ __launch_bounds__(256) void k_combine_ln(const bf16* __restrict__ dx,
      const float* __restrict__ lnw, const float* __restrict__ lnb,
      float* __restrict__ x){
  const int tid  = threadIdx.x;
  const int wv   = tid >> 6;
  const int lane = tid & 63;
  const int row  = blockIdx.x*8 + wv*2 + (lane >> 5);
  const int c0   = (lane & 31)*4;
  ushort4 d4 = *(const ushort4*)(dx + (size_t)row*128 + c0);
  float v0 = uphalf(d4.x), v1 = uphalf(d4.y), v2 = uphalf(d4.z), v3 = uphalf(d4.w);
  float s = (v0+v1)+(v2+v3);
  #pragma unroll
  for (int m=1;m<32;m<<=1) s += __shfl_xor(s, m);
  float mu = s * (1.f/128.f);
  float e0 = v0-mu, e1 = v1-mu, e2 = v2-mu, e3 = v3-mu;
  float q = (e0*e0+e1*e1)+(e2*e2+e3*e3);
  #pragma unroll
  for (int m=1;m<32;m<<=1) q += __shfl_xor(q, m);
  float rs = rsqrtf(q*(1.f/128.f) + 1e-5f);
  float4 w4 = *(const float4*)(lnw + c0);
  float4 b4 = *(const float4*)(lnb + c0);
  float4 xv = *(float4*)(x + (size_t)row*128 + c0);
  xv.x += e0*rs*w4.x + b4.x;
  xv.y += e1*rs*w4.y + b4.y;
  xv.z += e2*rs*w4.z + b4.z;
  xv.w += e3*rs*w4.w + b4.w;
  *(float4*)(x + (size_t)row*128 + c0) = xv;
}

// ---------------- pyramid gather ----------------
__global__ void k_pyramid(const float* __restrict__ x, float* __restrict__ out){
  int idx = blockIdx.x*256 + threadIdx.x;
  int j = idx & 31;
  int i = (idx >> 5) & 31;
  int c = (idx >> 10) & 127;
  int m = (idx >> 17) & 31;
  int o = idx >> 22;
  int base = o*1344;
  size_t xm = ((size_t)m * S_ + base) * 128 + c;
  float v = x[xm + (size_t)(320 + i*32 + j)*128]
          + x[xm + (size_t)(64 + (i>>1)*16 + (j>>1))*128]
          + x[xm + (size_t)((i>>2)*8 + (j>>2))*128];
  out[idx] = v;
}

extern "C" void kernel_launch(void* const* d_in, const int* in_sizes, int n_in,
                              void* d_out, int out_size, void* d_ws, size_t ws_size,
                              hipStream_t stream){
  const float* f0   = (const float*)d_in[0];
  const float* f1   = (const float*)d_in[1];
  const float* W_in = (const float*)d_in[2];
  const float* cw   = (const float*)d_in[3];
  const float* cb   = (const float*)d_in[4];
  const float* Wx   = (const float*)d_in[5];
  const float* Wdt  = (const float*)d_in[6];
  const float* bdt  = (const float*)d_in[7];
  const float* Alog = (const float*)d_in[8];
  const float* Dpar = (const float*)d_in[9];
  const float* Wout = (const float*)d_in[10];
  const float* lnw  = (const float*)d_in[11];
  const float* lnb  = (const float*)d_in[12];

  const size_t base = 214695936;
  int nc = 0;
  const int cand[6] = {84,42,21,12,6,2};
  for (int i=0;i<6;i++){
    size_t need = base + (size_t)32*cand[i]*256*16*4;
    if (ws_size >= need){ nc = cand[i]; break; }
  }
  if (nc == 0) return;
  const int cl = S_/nc;
  const int ncH = (nc+1) >> 1;

  char* ws = (char*)d_ws;
  float* x      = (float*)(ws + 0);
  bf16*  xi     = (bf16*) (ws + 44040192);
  bf16*  dtb    = (bf16*) (ws + 44040192);
  bf16*  z      = (bf16*) (ws + 88080384);
  bf16*  xc     = (bf16*) (ws + 132120576);
  float* BC     = (float*)(ws + 176160768);
  float* sumdt  = (float*)(ws + 187170816);
  bf16*  Wt_in  = (bf16*) (ws + 189923328);
  bf16*  Wt_out = (bf16*) (ws + 190447616);
  bf16*  Wxt    = (bf16*) (ws + 190709760);
  bf16*  dx     = (bf16*) (ws + 192675840);
  float* hend   = (float*)(ws + 214695936);

  k_init_x<<<43008,256,0,stream>>>(f0, f1, x);
  k_wconv <<<1728,256,0,stream>>>(W_in, Wx, Wout, Wt_in, Wxt, Wt_out);

  for (int l=0;l<2;l++){
    for (int r=0;r<2;r++){
      int lr = l*2 + r;
      const float* Al = Alog + (size_t)lr*256*16;
      k_gemm_in_mfma  <<<1344,256,0,stream>>>(x, Wt_in + (size_t)lr*65536, xi, z, r);
      k_conv_silu     <<<2688,256,0,stream>>>(xi, cw + lr*256*4, cb + lr*256, xc);
      k_gemm_x_dt_mfma<<<1344,256,0,stream>>>(xc, Wxt + (size_t)lr*12288,
                                              Wdt + (size_t)lr*8*256, bdt + lr*256, BC, dtb);
      if (cl == 32)
        k_scan_p1<32><<<32*ncH,256,0,stream>>>(xc, dtb, BC, Al, hend, sumdt, nc, cl);
      else if (cl == 64)
        k_scan_p1<64><<<32*ncH,256,0,stream>>>(xc, dtb, BC, Al, hend, sumdt, nc, cl);
      else
        k_scan_p1<0> <<<32*ncH,256,0,stream>>>(xc, dtb, BC, Al, hend, sumdt, nc, cl);
      k_scan_comb<<<512,256,0,stream>>>(Al, sumdt, hend, nc);
      if (cl == 32)
        k_scan_p2<32><<<32*ncH,256,0,stream>>>(xc, dtb, BC, z, Al, Dpar + lr*256,
                                               hend, xc, nc, cl);
      else if (cl == 64)
        k_scan_p2<64><<<32*ncH,256,0,stream>>>(xc, dtb, BC, z, Al, Dpar + lr*256,
                                               hend, xc, nc, cl);
      else
        k_scan_p2<0> <<<32*ncH,256,0,stream>>>(xc, dtb, BC, z, Al, Dpar + lr*256,
                                               hend, xc, nc, cl);
      k_gemm_out_mfma <<<2688,256,0,stream>>>(xc, Wt_out + (size_t)lr*32768, dx, r);
    }
    k_combine_ln<<<10752,256,0,stream>>>(dx, lnw + l*128, lnb + l*128, x);
  }

  k_pyramid<<<32768,256,0,stream>>>(x, (float*)d_out);
}

// Round 19
// 1175.849 us; speedup vs baseline: 1.0590x; 1.0590x over previous
//
#include <hip/hip_runtime.h>
#include <hip/hip_bf16.h>
#include <math.h>

#define B_   32
#define S_   2688
#define D_   128
#define DI_  256
#define DS_  16
#define NROWS (B_*S_)   // 86016

typedef __hip_bfloat16 bf16;
typedef float f32x4 __attribute__((ext_vector_type(4)));
typedef float f32x2 __attribute__((ext_vector_type(2)));
typedef short bf16x8 __attribute__((ext_vector_type(8)));
#define MFMA16(a,b,c) __builtin_amdgcn_mfma_f32_16x16x32_bf16(a,b,c,0,0,0)

__device__ __forceinline__ float bf2f(bf16 v){ return __bfloat162float(v); }
__device__ __forceinline__ bf16  f2bf(float f){ return __float2bfloat16(f); }
__device__ __forceinline__ float uphalf(unsigned short u){
  union { unsigned int i; float f; } c; c.i = ((unsigned int)u) << 16; return c.f;
}
__device__ __forceinline__ unsigned int pk2(float a, float b){
  unsigned int lo = __hip_bfloat16_raw(f2bf(a)).x;
  unsigned int hi = __hip_bfloat16_raw(f2bf(b)).x;
  return lo | (hi << 16);
}

// log(n+1) fp32 constants for the A_log pattern check.
__device__ __constant__ float LOGN[16] = {
  0.0f, 0.69314718056f, 1.09861228867f, 1.38629436112f,
  1.60943791243f, 1.79175946923f, 1.94591014906f, 2.07944154168f,
  2.19722457734f, 2.30258509299f, 2.39789527280f, 2.48490664979f,
  2.56494935746f, 2.63905732962f, 2.70805020110f, 2.77258872224f };

// dA2[i] = {exp(dt*A_{2i}), exp(dt*A_{2i+1})}.
// Fast path (ok): A_n = -(n+1) => dA = w^(n+1), w=exp(-dt); packed chain *w^2.
__device__ __forceinline__ void comp_dA2(f32x2 dA2[8], float dtv, bool ok,
                                         const f32x2 anl2[8]){
  if (ok){
    float w1 = __expf(-dtv);
    float w2 = w1*w1;
    f32x2 ww; ww.x = w2; ww.y = w2;
    dA2[0].x = w1; dA2[0].y = w2;
    #pragma unroll
    for (int i=1;i<8;i++) dA2[i] = dA2[i-1]*ww;
  } else {
    #pragma unroll
    for (int i=0;i<8;i++){
      dA2[i].x = exp2f(dtv*anl2[i].x);
      dA2[i].y = exp2f(dtv*anl2[i].y);
    }
  }
}

// ---------------- init: x = concat(feat0, feat1) along seq ----------------
__global__ void k_init_x(const float* __restrict__ f0, const float* __restrict__ f1,
                         float* __restrict__ x){
  int idx = blockIdx.x*256 + threadIdx.x;
  if (idx >= B_*S_*D_) return;
  const int per_b = S_*D_;
  const int half  = 1344*D_;
  int b = idx / per_b;
  int rem = idx - b*per_b;
  x[idx] = (rem < half) ? f0[b*half + rem] : f1[b*half + rem - half];
}

// -------- weight convert/transpose to bf16 ---------------------------------
__global__ void k_wconv(const float* __restrict__ W_in, const float* __restrict__ Wx,
                        const float* __restrict__ W_out,
                        bf16* __restrict__ Wt_in, bf16* __restrict__ Wxt,
                        bf16* __restrict__ Wt_out){
  int idx = blockIdx.x*256 + threadIdx.x;   // 1728*256 = 442368
  if (idx < 262144){
    int k = idx & 127, n = (idx>>7) & 511, lr = idx>>16;
    Wt_in[idx] = f2bf(W_in[((size_t)lr*128 + k)*512 + n]);
    return;
  }
  int i2 = idx - 262144;
  if (i2 < 131072){
    int k = i2 & 255, n = (i2>>8) & 127, lr = i2>>15;
    Wt_out[i2] = f2bf(W_out[((size_t)lr*256 + k)*128 + n]);
    return;
  }
  int i3 = i2 - 131072;
  if (i3 < 49152){
    int k = i3 & 255, nn = i3>>8, n = nn % 48, lr = nn / 48;
    Wxt[i3] = (n < 40) ? f2bf(Wx[((size_t)lr*256 + k)*40 + n]) : f2bf(0.f);
  }
}

// ------------- gemm_in (MFMA): [xi|z] = x(_rev) @ W_in ---------------------
__global__ __launch_bounds__(256) void k_gemm_in_mfma(const float* __restrict__ x,
      const bf16* __restrict__ Wt, bf16* __restrict__ xi, bf16* __restrict__ z, int rev){
  __shared__ __align__(16) unsigned short a_sh[64][136];
  __shared__ __align__(16) unsigned short b_sh[64][136];
  const int r0 = blockIdx.x*64;              // 1344 blocks
  const int b  = r0 / S_;
  const int t0 = r0 - b*S_;
  const int tid = threadIdx.x;
  const int lane = tid & 63, wv = tid >> 6;
  const int wr = (wv>>1)*32, wc = (wv&1)*32;
  const int fr = lane & 15, fk = (lane>>4)*8;

  #pragma unroll
  for (int q=0;q<4;q++){
    int fid = tid + 256*q;
    int r = fid >> 4, g = fid & 15;
    int t = t0 + r;
    int rg = b*S_ + (rev ? (S_-1 - t) : t);
    const float* src = x + (size_t)rg*128 + g*8;
    float4 v0 = *(const float4*)(src);
    float4 v1 = *(const float4*)(src + 4);
    uint4 pk;
    pk.x = pk2(v0.x, v0.y);
    pk.y = pk2(v0.z, v0.w);
    pk.z = pk2(v1.x, v1.y);
    pk.w = pk2(v1.z, v1.w);
    *(uint4*)&a_sh[r][g*8] = pk;
    *(uint4*)&b_sh[r][g*8] = *(const uint4*)(Wt + (size_t)r*128 + g*8);
  }
  __syncthreads();

  for (int bn=0;bn<8;bn++){
    if (bn){
      __syncthreads();
      #pragma unroll
      for (int q=0;q<4;q++){
        int fid = tid + 256*q;
        int r = fid >> 4, g = fid & 15;
        *(uint4*)&b_sh[r][g*8] = *(const uint4*)(Wt + (size_t)(bn*64+r)*128 + g*8);
      }
      __syncthreads();
    }
    const f32x4 zero = {0.f,0.f,0.f,0.f};
    f32x4 acc[2][2] = {{zero,zero},{zero,zero}};
    #pragma unroll
    for (int ks=0;ks<4;ks++){
      bf16x8 a0 = *(const bf16x8*)&a_sh[wr+fr   ][ks*32+fk];
      bf16x8 a1 = *(const bf16x8*)&a_sh[wr+16+fr][ks*32+fk];
      bf16x8 b0 = *(const bf16x8*)&b_sh[wc+fr   ][ks*32+fk];
      bf16x8 b1 = *(const bf16x8*)&b_sh[wc+16+fr][ks*32+fk];
      acc[0][0] = MFMA16(a0,b0,acc[0][0]);
      acc[0][1] = MFMA16(a0,b1,acc[0][1]);
      acc[1][0] = MFMA16(a1,b0,acc[1][0]);
      acc[1][1] = MFMA16(a1,b1,acc[1][1]);
    }
    #pragma unroll
    for (int fi=0;fi<2;fi++){
      #pragma unroll
      for (int fj=0;fj<2;fj++){
        int gcol = bn*64 + wc + fj*16 + fr;
        bf16* dst = (gcol < 256) ? xi : z;
        int cc = gcol & 255;
        #pragma unroll
        for (int r=0;r<4;r++){
          size_t row = (size_t)(r0 + wr + fi*16 + (lane>>4)*4 + r);
          dst[row*256 + cc] = f2bf(acc[fi][fj][r]);
        }
      }
    }
  }
}

// ------- conv + silu (vectorized: 4 rows x 8 channels per thread) ----------
__global__ __launch_bounds__(256) void k_conv_silu(const bf16* __restrict__ xi,
      const float* __restrict__ cw, const float* __restrict__ cb,
      bf16* __restrict__ xc){
  int gid = blockIdx.x*256 + threadIdx.x;
  int dg  = gid & 31;
  int rg  = gid >> 5;
  const int r0 = rg*4;
  const int t0 = r0 % S_;
  const int d0 = dg*8;

  uint4 w[7];
  const uint4 z4 = make_uint4(0,0,0,0);
  #pragma unroll
  for (int i=0;i<7;i++){
    int off = i - 3;
    if (t0 == 0 && i < 3) w[i] = z4;
    else w[i] = *(const uint4*)(xi + (size_t)(r0+off)*256 + d0);
  }
  float f[7][8];
  #pragma unroll
  for (int i=0;i<7;i++){
    unsigned int ww[4] = {w[i].x, w[i].y, w[i].z, w[i].w};
    #pragma unroll
    for (int p=0;p<4;p++){
      f[i][p*2+0] = uphalf((unsigned short)(ww[p] & 0xffffu));
      f[i][p*2+1] = uphalf((unsigned short)(ww[p] >> 16));
    }
  }
  float wt[8][4], bias[8];
  #pragma unroll
  for (int c2=0;c2<2;c2++){
    float4 b4 = *(const float4*)(cb + d0 + c2*4);
    bias[c2*4+0]=b4.x; bias[c2*4+1]=b4.y; bias[c2*4+2]=b4.z; bias[c2*4+3]=b4.w;
  }
  #pragma unroll
  for (int c=0;c<8;c++){
    float4 w4 = *(const float4*)(cw + (d0+c)*4);
    wt[c][0]=w4.x; wt[c][1]=w4.y; wt[c][2]=w4.z; wt[c][3]=w4.w;
  }
  #pragma unroll
  for (int k=0;k<4;k++){
    unsigned int owords[4];
    #pragma unroll
    for (int p=0;p<4;p++){
      float o2[2];
      #pragma unroll
      for (int h=0;h<2;h++){
        int c = p*2+h;
        float acc = bias[c];
        #pragma unroll
        for (int j=0;j<4;j++) acc = fmaf(wt[c][j], f[k+j][c], acc);
        float sig = 1.f/(1.f + __expf(-acc));
        o2[h] = acc*sig;
      }
      owords[p] = pk2(o2[0], o2[1]);
    }
    uint4 outv = make_uint4(owords[0],owords[1],owords[2],owords[3]);
    *(uint4*)(xc + (size_t)(r0+k)*256 + d0) = outv;
  }
}

// -- gemm_x+dt (MFMA): xdbl = xc@Wx; BC[row][32]=B|C; dtb=softplus(dbl@Wdt+b)
__global__ __launch_bounds__(256) void k_gemm_x_dt_mfma(const bf16* __restrict__ xc,
      const bf16* __restrict__ Wxt, const float* __restrict__ Wdt, const float* __restrict__ bdt,
      float* __restrict__ BC, bf16* __restrict__ dtb){
  __shared__ __align__(16) unsigned short a_sh[64][136];
  __shared__ __align__(16) unsigned short b_sh[48][136];
  __shared__ __align__(16) float s_dbl[64][8];
  const int r0 = blockIdx.x*64;              // 1344 blocks
  const int tid = threadIdx.x;
  const int lane = tid & 63, wv = tid >> 6;
  const int fr = lane & 15, fk = (lane>>4)*8;
  const f32x4 zero = {0.f,0.f,0.f,0.f};
  f32x4 acc[3] = {zero,zero,zero};

  for (int kst=0;kst<2;kst++){
    if (kst) __syncthreads();
    #pragma unroll
    for (int q=0;q<4;q++){
      int fid = tid + 256*q;
      int r = fid >> 4, g = fid & 15;
      *(uint4*)&a_sh[r][g*8] = *(const uint4*)(xc + (size_t)(r0+r)*256 + kst*128 + g*8);
      if (fid < 768)
        *(uint4*)&b_sh[r][g*8] = *(const uint4*)(Wxt + (size_t)r*256 + kst*128 + g*8);
    }
    __syncthreads();
    #pragma unroll
    for (int ks=0;ks<4;ks++){
      bf16x8 a0 = *(const bf16x8*)&a_sh[wv*16+fr][ks*32+fk];
      #pragma unroll
      for (int fj=0;fj<3;fj++){
        bf16x8 bb = *(const bf16x8*)&b_sh[fj*16+fr][ks*32+fk];
        acc[fj] = MFMA16(a0,bb,acc[fj]);
      }
    }
  }
  #pragma unroll
  for (int fj=0;fj<3;fj++){
    int col = fj*16 + fr;
    #pragma unroll
    for (int r=0;r<4;r++){
      int rr = wv*16 + (lane>>4)*4 + r;
      size_t row = (size_t)(r0 + rr);
      if (col < 8)       s_dbl[rr][col] = acc[fj][r];
      else if (col < 40) BC[row*32 + (col-8)] = acc[fj][r];
    }
  }
  __syncthreads();
  float wdt[8];
  #pragma unroll
  for (int j=0;j<8;j++) wdt[j] = Wdt[j*256 + tid];
  float bd = bdt[tid];
  #pragma unroll
  for (int r=0;r<64;r++){
    float4 d0 = *(const float4*)&s_dbl[r][0];
    float4 d1 = *(const float4*)&s_dbl[r][4];
    float v = bd;
    v = fmaf(d0.x, wdt[0], v);
    v = fmaf(d0.y, wdt[1], v);
    v = fmaf(d0.z, wdt[2], v);
    v = fmaf(d0.w, wdt[3], v);
    v = fmaf(d1.x, wdt[4], v);
    v = fmaf(d1.y, wdt[5], v);
    v = fmaf(d1.z, wdt[6], v);
    v = fmaf(d1.w, wdt[7], v);
    float sp = (v > 20.f) ? v : __logf(1.f + __expf(v));
    dtb[(size_t)(r0+r)*256 + tid] = f2bf(sp);
  }
}

// ==== chunked scan (2 ch/thread, BC staged in LDS, packed fp32) =============
__device__ __forceinline__ bool load_A(const float* Alog, int d, f32x2 anl2[8]){
  const float4* ap = (const float4*)(Alog + d*16);
  float4 a0=ap[0], a1=ap[1], a2=ap[2], a3=ap[3];
  float tmp[16] = {a0.x,a0.y,a0.z,a0.w, a1.x,a1.y,a1.z,a1.w,
                   a2.x,a2.y,a2.z,a2.w, a3.x,a3.y,a3.z,a3.w};
  bool ok = true;
  #pragma unroll
  for (int n=0;n<16;n++) ok = ok && (fabsf(tmp[n] - LOGN[n]) < 1e-4f);
  if (!ok){
    #pragma unroll
    for (int i=0;i<8;i++){
      anl2[i].x = -__expf(tmp[i*2+0]) * 1.44269504f;
      anl2[i].y = -__expf(tmp[i*2+1]) * 1.44269504f;
    }
  }
  return ok;
}

__device__ __forceinline__ void unpackBC(const float4 v[4], f32x2 o[8]){
  o[0].x=v[0].x; o[0].y=v[0].y;  o[1].x=v[0].z; o[1].y=v[0].w;
  o[2].x=v[1].x; o[2].y=v[1].y;  o[3].x=v[1].z; o[3].y=v[1].w;
  o[4].x=v[2].x; o[4].y=v[2].y;  o[5].x=v[2].z; o[5].y=v[2].w;
  o[6].x=v[3].x; o[6].y=v[3].y;  o[7].x=v[3].z; o[7].y=v[3].w;
}

template<int CL>
__global__ __launch_bounds__(128) void k_scan_p1(const bf16* __restrict__ xc,
      const bf16* __restrict__ dtb, const float* __restrict__ BC,
      const float* __restrict__ Alog,
      float* __restrict__ hend, float* __restrict__ sumdt, int nc, int cl_rt){
  __shared__ __align__(16) float bcsh[CL ? CL : 1][32];
  const int blk = blockIdx.x;
  const int b = blk / nc;
  const int c = blk - b*nc;
  const int d0 = threadIdx.x*2;
  const int cl = CL ? CL : cl_rt;
  const size_t rowbase = (size_t)b*S_ + (size_t)c*cl;
  if (CL){
    for (int i = threadIdx.x; i < CL*8; i += 128){
      int rr = i >> 3, q = i & 7;
      *(float4*)&bcsh[rr][q*4] = *(const float4*)(BC + (rowbase+rr)*32 + q*4);
    }
    __syncthreads();
  }
  f32x2 anlA[8], anlB[8];
  const bool okA = load_A(Alog, d0,   anlA);
  const bool okB = load_A(Alog, d0+1, anlB);
  f32x2 hA[8], hB[8];
  #pragma unroll
  for (int i=0;i<8;i++){ hA[i].x=0.f; hA[i].y=0.f; hB[i].x=0.f; hB[i].y=0.f; }
  float sA = 0.f, sB = 0.f;
  #pragma unroll 2
  for (int t=0;t<cl;t++){
    size_t row = rowbase + t;
    unsigned int dtp = *(const unsigned int*)(dtb + row*256 + d0);
    unsigned int up  = *(const unsigned int*)(xc  + row*256 + d0);
    float dtA = uphalf((unsigned short)(dtp & 0xffffu));
    float dtB = uphalf((unsigned short)(dtp >> 16));
    float uA  = uphalf((unsigned short)(up  & 0xffffu));
    float uB  = uphalf((unsigned short)(up  >> 16));
    sA += dtA; sB += dtB;
    const float4* bp = CL ? (const float4*)&bcsh[t][0]
                          : (const float4*)(BC + row*32);
    float4 Bv[4] = {bp[0], bp[1], bp[2], bp[3]};
    f32x2 B2[8];
    unpackBC(Bv, B2);
    f32x2 duA; duA.x = dtA*uA; duA.y = dtA*uA;
    f32x2 duB; duB.x = dtB*uB; duB.y = dtB*uB;
    f32x2 dAA[8], dAB[8];
    comp_dA2(dAA, dtA, okA, anlA);
    comp_dA2(dAB, dtB, okB, anlB);
    #pragma unroll
    for (int i=0;i<8;i++){
      hA[i] = dAA[i]*hA[i] + duA*B2[i];
      hB[i] = dAB[i]*hB[i] + duB*B2[i];
    }
  }
  float4* hp = (float4*)(hend + ((size_t)blk*256 + d0)*16);
  hp[0] = make_float4(hA[0].x,hA[0].y,hA[1].x,hA[1].y);
  hp[1] = make_float4(hA[2].x,hA[2].y,hA[3].x,hA[3].y);
  hp[2] = make_float4(hA[4].x,hA[4].y,hA[5].x,hA[5].y);
  hp[3] = make_float4(hA[6].x,hA[6].y,hA[7].x,hA[7].y);
  hp[4] = make_float4(hB[0].x,hB[0].y,hB[1].x,hB[1].y);
  hp[5] = make_float4(hB[2].x,hB[2].y,hB[3].x,hB[3].y);
  hp[6] = make_float4(hB[4].x,hB[4].y,hB[5].x,hB[5].y);
  hp[7] = make_float4(hB[6].x,hB[6].y,hB[7].x,hB[7].y);
  *(float2*)(sumdt + (size_t)blk*256 + d0) = make_float2(sA, sB);
}

// --- combine: one (b,d,n) scalar chain per thread; 512 blocks --------------
__global__ __launch_bounds__(256) void k_scan_comb(const float* __restrict__ Alog,
      const float* __restrict__ sumdt, float* __restrict__ hend, int nc){
  const int blk = blockIdx.x;
  const int b  = blk >> 4;
  const int dg = blk & 15;
  const int tid = threadIdx.x;
  const int dl = tid >> 4;
  const int n  = tid & 15;
  const int d  = dg*16 + dl;
  const float anl2 = -__expf(Alog[d*16 + n]) * 1.44269504f;
  float carry = 0.f;
  const size_t basei = (size_t)b*nc;
  for (int c=0;c<nc;c++){
    size_t blkc = basei + c;
    size_t hidx = (blkc*256 + d)*16 + n;
    float he  = hend[hidx];
    float sdt = sumdt[blkc*256 + d];
    hend[hidx] = carry;
    carry = fmaf(exp2f(sdt*anl2), carry, he);
  }
}

template<int CL>
__global__ __launch_bounds__(128) void k_scan_p2(const bf16* __restrict__ xcin,
      const bf16* __restrict__ dtb, const float* __restrict__ BC,
      const bf16* __restrict__ zb, const float* __restrict__ Alog,
      const float* __restrict__ Dpar, const float* __restrict__ hend,
      bf16* __restrict__ ym, int nc, int cl_rt){
  __shared__ __align__(16) float bcsh[CL ? CL : 1][32];
  const int blk = blockIdx.x;
  const int b = blk / nc;
  const int c = blk - b*nc;
  const int d0 = threadIdx.x*2;
  const int cl = CL ? CL : cl_rt;
  const size_t rowbase = (size_t)b*S_ + (size_t)c*cl;
  if (CL){
    for (int i = threadIdx.x; i < CL*8; i += 128){
      int rr = i >> 3, q = i & 7;
      *(float4*)&bcsh[rr][q*4] = *(const float4*)(BC + (rowbase+rr)*32 + q*4);
    }
    __syncthreads();
  }
  f32x2 anlA[8], anlB[8];
  const bool okA = load_A(Alog, d0,   anlA);
  const bool okB = load_A(Alog, d0+1, anlB);
  float2 Dp2 = *(const float2*)(Dpar + d0);
  f32x2 hA[8], hB[8];
  {
    const float4* hp = (const float4*)(hend + ((size_t)blk*256 + d0)*16);
    float4 v0=hp[0], v1=hp[1], v2=hp[2], v3=hp[3];
    float4 v4=hp[4], v5=hp[5], v6=hp[6], v7=hp[7];
    hA[0].x=v0.x; hA[0].y=v0.y;  hA[1].x=v0.z; hA[1].y=v0.w;
    hA[2].x=v1.x; hA[2].y=v1.y;  hA[3].x=v1.z; hA[3].y=v1.w;
    hA[4].x=v2.x; hA[4].y=v2.y;  hA[5].x=v2.z; hA[5].y=v2.w;
    hA[6].x=v3.x; hA[6].y=v3.y;  hA[7].x=v3.z; hA[7].y=v3.w;
    hB[0].x=v4.x; hB[0].y=v4.y;  hB[1].x=v4.z; hB[1].y=v4.w;
    hB[2].x=v5.x; hB[2].y=v5.y;  hB[3].x=v5.z; hB[3].y=v5.w;
    hB[4].x=v6.x; hB[4].y=v6.y;  hB[5].x=v6.z; hB[5].y=v6.w;
    hB[6].x=v7.x; hB[6].y=v7.y;  hB[7].x=v7.z; hB[7].y=v7.w;
  }
  #pragma unroll 2
  for (int t=0;t<cl;t++){
    size_t row = rowbase + t;
    unsigned int dtp = *(const unsigned int*)(dtb  + row*256 + d0);
    unsigned int up  = *(const unsigned int*)(xcin + row*256 + d0);
    unsigned int zp  = *(const unsigned int*)(zb   + row*256 + d0);
    float dtA = uphalf((unsigned short)(dtp & 0xffffu));
    float dtB = uphalf((unsigned short)(dtp >> 16));
    float uA  = uphalf((unsigned short)(up  & 0xffffu));
    float uB  = uphalf((unsigned short)(up  >> 16));
    const float4* bp = CL ? (const float4*)&bcsh[t][0]
                          : (const float4*)(BC + row*32);
    float4 Bv[4] = {bp[0], bp[1], bp[2], bp[3]};
    float4 Cv[4] = {bp[4], bp[5], bp[6], bp[7]};
    f32x2 B2[8], C2[8];
    unpackBC(Bv, B2);
    unpackBC(Cv, C2);
    f32x2 duA; duA.x = dtA*uA; duA.y = dtA*uA;
    f32x2 duB; duB.x = dtB*uB; duB.y = dtB*uB;
    f32x2 dAA[8], dAB[8];
    comp_dA2(dAA, dtA, okA, anlA);
    comp_dA2(dAB, dtB, okB, anlB);
    f32x2 accA; accA.x=0.f; accA.y=0.f;
    f32x2 accB; accB.x=0.f; accB.y=0.f;
    #pragma unroll
    for (int i=0;i<8;i++){
      hA[i] = dAA[i]*hA[i] + duA*B2[i];
      hB[i] = dAB[i]*hB[i] + duB*B2[i];
      accA = accA + hA[i]*C2[i];
      accB = accB + hB[i]*C2[i];
    }
    float pA = accA.x + accA.y;
    float pB = accB.x + accB.y;
    float yA = fmaf(uA, Dp2.x, pA);
    float yB = fmaf(uB, Dp2.y, pB);
    float zA = uphalf((unsigned short)(zp & 0xffffu));
    float zB = uphalf((unsigned short)(zp >> 16));
    float gA = zA / (1.f + __expf(-zA));
    float gB = zB / (1.f + __expf(-zB));
    *(unsigned int*)(ym + row*256 + d0) = pk2(yA*gA, yB*gB);
  }
}

// ------- gemm_out (MFMA): dx = ym @ W_out (K=256), fwd/bwd-fold ------------
__global__ __launch_bounds__(256) void k_gemm_out_mfma(const bf16* __restrict__ ym,
      const bf16* __restrict__ Wt, bf16* __restrict__ dx, int rev){
  __shared__ __align__(16) unsigned short a_sh[64][136];
  __shared__ __align__(16) unsigned short b_sh[64][136];
  const int blk = blockIdx.x;                // 1344 * 2
  const int bm = blk >> 1, bn = blk & 1;
  const int r0 = bm*64, n0 = bn*64;
  const int b  = r0 / S_;
  const int t0 = r0 - b*S_;
  const int tid = threadIdx.x;
  const int lane = tid & 63, wv = tid >> 6;
  const int wr = (wv>>1)*32, wc = (wv&1)*32;
  const int fr = lane & 15, fk = (lane>>4)*8;
  const f32x4 zero = {0.f,0.f,0.f,0.f};
  f32x4 acc[2][2] = {{zero,zero},{zero,zero}};

  for (int kst=0;kst<2;kst++){
    if (kst) __syncthreads();
    #pragma unroll
    for (int q=0;q<4;q++){
      int fid = tid + 256*q;
      int r = fid >> 4, g = fid & 15;
      *(uint4*)&a_sh[r][g*8] = *(const uint4*)(ym + (size_t)(r0+r)*256 + kst*128 + g*8);
      *(uint4*)&b_sh[r][g*8] = *(const uint4*)(Wt + (size_t)(n0+r)*256 + kst*128 + g*8);
    }
    __syncthreads();
    #pragma unroll
    for (int ks=0;ks<4;ks++){
      bf16x8 a0 = *(const bf16x8*)&a_sh[wr+fr   ][ks*32+fk];
      bf16x8 a1 = *(const bf16x8*)&a_sh[wr+16+fr][ks*32+fk];
      bf16x8 b0 = *(const bf16x8*)&b_sh[wc+fr   ][ks*32+fk];
      bf16x8 b1 = *(const bf16x8*)&b_sh[wc+16+fr][ks*32+fk];
      acc[0][0] = MFMA16(a0,b0,acc[0][0]);
      acc[0][1] = MFMA16(a0,b1,acc[0][1]);
      acc[1][0] = MFMA16(a1,b0,acc[1][0]);
      acc[1][1] = MFMA16(a1,b1,acc[1][1]);
    }
  }
  #pragma unroll
  for (int fi=0;fi<2;fi++){
    #pragma unroll
    for (int fj=0;fj<2;fj++){
      int c = n0 + wc + fj*16 + fr;
      #pragma unroll
      for (int r=0;r<4;r++){
        int t = t0 + wr + fi*16 + (lane>>4)*4 + r;
        size_t drow = (size_t)b*S_ + (rev ? (S_-1 - t) : t);
        if (rev){
          float old = bf2f(dx[drow*128 + c]);
          dx[drow*128 + c] = f2bf(old + 0.5f*acc[fi][fj][r]);
        } else {
          dx[drow*128 + c] = f2bf(0.5f*acc[fi][fj][r]);
        }
      }
    }
  }
}

// --- combine + layernorm + residual (vectorized: 4 ch/lane, 2 rows/wave) ---
__global__ __launch_bounds__(256) void k_combine_ln(const bf16* __restrict__ dx,
      const float* __restrict__ lnw, const float* __restrict__ lnb,
      float* __restrict__ x){
  const int tid  = threadIdx.x;
  const int wv   = tid >> 6;
  const int lane = tid & 63;
  const int row  = blockIdx.x*8 + wv*2 + (lane >> 5);
  const int c0   = (lane & 31)*4;
  ushort4 d4 = *(const ushort4*)(dx + (size_t)row*128 + c0);
  float v0 = uphalf(d4.x), v1 = uphalf(d4.y), v2 = uphalf(d4.z), v3 = uphalf(d4.w);
  float s = (v0+v1)+(v2+v3);
  #pragma unroll
  for (int m=1;m<32;m<<=1) s += __shfl_xor(s, m);
  float mu = s * (1.f/128.f);
  float e0 = v0-mu, e1 = v1-mu, e2 = v2-mu, e3 = v3-mu;
  float q = (e0*e0+e1*e1)+(e2*e2+e3*e3);
  #pragma unroll
  for (int m=1;m<32;m<<=1) q += __shfl_xor(q, m);
  float rs = rsqrtf(q*(1.f/128.f) + 1e-5f);
  float4 w4 = *(const float4*)(lnw + c0);
  float4 b4 = *(const float4*)(lnb + c0);
  float4 xv = *(float4*)(x + (size_t)row*128 + c0);
  xv.x += e0*rs*w4.x + b4.x;
  xv.y += e1*rs*w4.y + b4.y;
  xv.z += e2*rs*w4.z + b4.z;
  xv.w += e3*rs*w4.w + b4.w;
  *(float4*)(x + (size_t)row*128 + c0) = xv;
}

// ---------------- pyramid gather ----------------
__global__ void k_pyramid(const float* __restrict__ x, float* __restrict__ out){
  int idx = blockIdx.x*256 + threadIdx.x;
  int j = idx & 31;
  int i = (idx >> 5) & 31;
  int c = (idx >> 10) & 127;
  int m = (idx >> 17) & 31;
  int o = idx >> 22;
  int base = o*1344;
  size_t xm = ((size_t)m * S_ + base) * 128 + c;
  float v = x[xm + (size_t)(320 + i*32 + j)*128]
          + x[xm + (size_t)(64 + (i>>1)*16 + (j>>1))*128]
          + x[xm + (size_t)((i>>2)*8 + (j>>2))*128];
  out[idx] = v;
}

extern "C" void kernel_launch(void* const* d_in, const int* in_sizes, int n_in,
                              void* d_out, int out_size, void* d_ws, size_t ws_size,
                              hipStream_t stream){
  const float* f0   = (const float*)d_in[0];
  const float* f1   = (const float*)d_in[1];
  const float* W_in = (const float*)d_in[2];
  const float* cw   = (const float*)d_in[3];
  const float* cb   = (const float*)d_in[4];
  const float* Wx   = (const float*)d_in[5];
  const float* Wdt  = (const float*)d_in[6];
  const float* bdt  = (const float*)d_in[7];
  const float* Alog = (const float*)d_in[8];
  const float* Dpar = (const float*)d_in[9];
  const float* Wout = (const float*)d_in[10];
  const float* lnw  = (const float*)d_in[11];
  const float* lnb  = (const float*)d_in[12];

  const size_t base = 214695936;
  int nc = 0;
  const int cand[6] = {84,42,21,12,6,2};
  for (int i=0;i<6;i++){
    size_t need = base + (size_t)32*cand[i]*256*16*4;
    if (ws_size >= need){ nc = cand[i]; break; }
  }
  if (nc == 0) return;
  const int cl = S_/nc;

  char* ws = (char*)d_ws;
  float* x      = (float*)(ws + 0);
  bf16*  xi     = (bf16*) (ws + 44040192);
  bf16*  dtb    = (bf16*) (ws + 44040192);
  bf16*  z      = (bf16*) (ws + 88080384);
  bf16*  xc     = (bf16*) (ws + 132120576);
  float* BC     = (float*)(ws + 176160768);
  float* sumdt  = (float*)(ws + 187170816);
  bf16*  Wt_in  = (bf16*) (ws + 189923328);
  bf16*  Wt_out = (bf16*) (ws + 190447616);
  bf16*  Wxt    = (bf16*) (ws + 190709760);
  bf16*  dx     = (bf16*) (ws + 192675840);
  float* hend   = (float*)(ws + 214695936);

  k_init_x<<<43008,256,0,stream>>>(f0, f1, x);
  k_wconv <<<1728,256,0,stream>>>(W_in, Wx, Wout, Wt_in, Wxt, Wt_out);

  for (int l=0;l<2;l++){
    for (int r=0;r<2;r++){
      int lr = l*2 + r;
      const float* Al = Alog + (size_t)lr*256*16;
      k_gemm_in_mfma  <<<1344,256,0,stream>>>(x, Wt_in + (size_t)lr*65536, xi, z, r);
      k_conv_silu     <<<2688,256,0,stream>>>(xi, cw + lr*256*4, cb + lr*256, xc);
      k_gemm_x_dt_mfma<<<1344,256,0,stream>>>(xc, Wxt + (size_t)lr*12288,
                                              Wdt + (size_t)lr*8*256, bdt + lr*256, BC, dtb);
      if (cl == 32)
        k_scan_p1<32><<<32*nc,128,0,stream>>>(xc, dtb, BC, Al, hend, sumdt, nc, cl);
      else if (cl == 64)
        k_scan_p1<64><<<32*nc,128,0,stream>>>(xc, dtb, BC, Al, hend, sumdt, nc, cl);
      else
        k_scan_p1<0> <<<32*nc,128,0,stream>>>(xc, dtb, BC, Al, hend, sumdt, nc, cl);
      k_scan_comb<<<512,256,0,stream>>>(Al, sumdt, hend, nc);
      if (cl == 32)
        k_scan_p2<32><<<32*nc,128,0,stream>>>(xc, dtb, BC, z, Al, Dpar + lr*256,
                                              hend, xc, nc, cl);
      else if (cl == 64)
        k_scan_p2<64><<<32*nc,128,0,stream>>>(xc, dtb, BC, z, Al, Dpar + lr*256,
                                              hend, xc, nc, cl);
      else
        k_scan_p2<0> <<<32*nc,128,0,stream>>>(xc, dtb, BC, z, Al, Dpar + lr*256,
                                              hend, xc, nc, cl);
      k_gemm_out_mfma <<<2688,256,0,stream>>>(xc, Wt_out + (size_t)lr*32768, dx, r);
    }
    k_combine_ln<<<10752,256,0,stream>>>(dx, lnw + l*128, lnb + l*128, x);
  }

  k_pyramid<<<32768,256,0,stream>>>(x, (float*)d_out);
}

// Round 20
// 1115.264 us; speedup vs baseline: 1.1165x; 1.0543x over previous
//
#include <hip/hip_runtime.h>
#include <hip/hip_bf16.h>
#include <math.h>

#define B_   32
#define S_   2688
#define D_   128
#define DI_  256
#define DS_  16
#define NROWS (B_*S_)   // 86016

typedef __hip_bfloat16 bf16;
typedef float f32x4 __attribute__((ext_vector_type(4)));
typedef float f32x2 __attribute__((ext_vector_type(2)));
typedef short bf16x8 __attribute__((ext_vector_type(8)));
#define MFMA16(a,b,c) __builtin_amdgcn_mfma_f32_16x16x32_bf16(a,b,c,0,0,0)

__device__ __forceinline__ float bf2f(bf16 v){ return __bfloat162float(v); }
__device__ __forceinline__ bf16  f2bf(float f){ return __float2bfloat16(f); }
__device__ __forceinline__ float uphalf(unsigned short u){
  union { unsigned int i; float f; } c; c.i = ((unsigned int)u) << 16; return c.f;
}
__device__ __forceinline__ unsigned int pk2(float a, float b){
  unsigned int lo = __hip_bfloat16_raw(f2bf(a)).x;
  unsigned int hi = __hip_bfloat16_raw(f2bf(b)).x;
  return lo | (hi << 16);
}

// log(n+1) fp32 constants for the A_log pattern check.
__device__ __constant__ float LOGN[16] = {
  0.0f, 0.69314718056f, 1.09861228867f, 1.38629436112f,
  1.60943791243f, 1.79175946923f, 1.94591014906f, 2.07944154168f,
  2.19722457734f, 2.30258509299f, 2.39789527280f, 2.48490664979f,
  2.56494935746f, 2.63905732962f, 2.70805020110f, 2.77258872224f };

// dA2[i] = {exp(dt*A_{2i}), exp(dt*A_{2i+1})}.
// Fast path (ok): A_n = -(n+1) => dA = w^(n+1), w=exp(-dt); packed chain *w^2.
__device__ __forceinline__ void comp_dA2(f32x2 dA2[8], float dtv, bool ok,
                                         const f32x2 anl2[8]){
  if (ok){
    float w1 = __expf(-dtv);
    float w2 = w1*w1;
    f32x2 ww; ww.x = w2; ww.y = w2;
    dA2[0].x = w1; dA2[0].y = w2;
    #pragma unroll
    for (int i=1;i<8;i++) dA2[i] = dA2[i-1]*ww;
  } else {
    #pragma unroll
    for (int i=0;i<8;i++){
      dA2[i].x = exp2f(dtv*anl2[i].x);
      dA2[i].y = exp2f(dtv*anl2[i].y);
    }
  }
}

// ---------------- init: x = concat(feat0, feat1) along seq ----------------
__global__ void k_init_x(const float* __restrict__ f0, const float* __restrict__ f1,
                         float* __restrict__ x){
  int idx = blockIdx.x*256 + threadIdx.x;
  if (idx >= B_*S_*D_) return;
  const int per_b = S_*D_;
  const int half  = 1344*D_;
  int b = idx / per_b;
  int rem = idx - b*per_b;
  x[idx] = (rem < half) ? f0[b*half + rem] : f1[b*half + rem - half];
}

// -------- weight convert/transpose to bf16 ---------------------------------
__global__ void k_wconv(const float* __restrict__ W_in, const float* __restrict__ Wx,
                        const float* __restrict__ W_out,
                        bf16* __restrict__ Wt_in, bf16* __restrict__ Wxt,
                        bf16* __restrict__ Wt_out){
  int idx = blockIdx.x*256 + threadIdx.x;   // 1728*256 = 442368
  if (idx < 262144){
    int k = idx & 127, n = (idx>>7) & 511, lr = idx>>16;
    Wt_in[idx] = f2bf(W_in[((size_t)lr*128 + k)*512 + n]);
    return;
  }
  int i2 = idx - 262144;
  if (i2 < 131072){
    int k = i2 & 255, n = (i2>>8) & 127, lr = i2>>15;
    Wt_out[i2] = f2bf(W_out[((size_t)lr*256 + k)*128 + n]);
    return;
  }
  int i3 = i2 - 131072;
  if (i3 < 49152){
    int k = i3 & 255, nn = i3>>8, n = nn % 48, lr = nn / 48;
    Wxt[i3] = (n < 40) ? f2bf(Wx[((size_t)lr*256 + k)*40 + n]) : f2bf(0.f);
  }
}

// --- gemm_in (MFMA): [xi|z] = x(_rev) @ W_in; z half stored as silu(z) -----
__global__ __launch_bounds__(256) void k_gemm_in_mfma(const float* __restrict__ x,
      const bf16* __restrict__ Wt, bf16* __restrict__ xi, bf16* __restrict__ z, int rev){
  __shared__ __align__(16) unsigned short a_sh[64][136];
  __shared__ __align__(16) unsigned short b_sh[64][136];
  const int r0 = blockIdx.x*64;              // 1344 blocks
  const int b  = r0 / S_;
  const int t0 = r0 - b*S_;
  const int tid = threadIdx.x;
  const int lane = tid & 63, wv = tid >> 6;
  const int wr = (wv>>1)*32, wc = (wv&1)*32;
  const int fr = lane & 15, fk = (lane>>4)*8;

  #pragma unroll
  for (int q=0;q<4;q++){
    int fid = tid + 256*q;
    int r = fid >> 4, g = fid & 15;
    int t = t0 + r;
    int rg = b*S_ + (rev ? (S_-1 - t) : t);
    const float* src = x + (size_t)rg*128 + g*8;
    float4 v0 = *(const float4*)(src);
    float4 v1 = *(const float4*)(src + 4);
    uint4 pk;
    pk.x = pk2(v0.x, v0.y);
    pk.y = pk2(v0.z, v0.w);
    pk.z = pk2(v1.x, v1.y);
    pk.w = pk2(v1.z, v1.w);
    *(uint4*)&a_sh[r][g*8] = pk;
    *(uint4*)&b_sh[r][g*8] = *(const uint4*)(Wt + (size_t)r*128 + g*8);
  }
  __syncthreads();

  for (int bn=0;bn<8;bn++){
    if (bn){
      __syncthreads();
      #pragma unroll
      for (int q=0;q<4;q++){
        int fid = tid + 256*q;
        int r = fid >> 4, g = fid & 15;
        *(uint4*)&b_sh[r][g*8] = *(const uint4*)(Wt + (size_t)(bn*64+r)*128 + g*8);
      }
      __syncthreads();
    }
    const f32x4 zero = {0.f,0.f,0.f,0.f};
    f32x4 acc[2][2] = {{zero,zero},{zero,zero}};
    #pragma unroll
    for (int ks=0;ks<4;ks++){
      bf16x8 a0 = *(const bf16x8*)&a_sh[wr+fr   ][ks*32+fk];
      bf16x8 a1 = *(const bf16x8*)&a_sh[wr+16+fr][ks*32+fk];
      bf16x8 b0 = *(const bf16x8*)&b_sh[wc+fr   ][ks*32+fk];
      bf16x8 b1 = *(const bf16x8*)&b_sh[wc+16+fr][ks*32+fk];
      acc[0][0] = MFMA16(a0,b0,acc[0][0]);
      acc[0][1] = MFMA16(a0,b1,acc[0][1]);
      acc[1][0] = MFMA16(a1,b0,acc[1][0]);
      acc[1][1] = MFMA16(a1,b1,acc[1][1]);
    }
    #pragma unroll
    for (int fi=0;fi<2;fi++){
      #pragma unroll
      for (int fj=0;fj<2;fj++){
        int gcol = bn*64 + wc + fj*16 + fr;
        bool isz = (gcol >= 256);
        bf16* dst = isz ? z : xi;
        int cc = gcol & 255;
        #pragma unroll
        for (int r=0;r<4;r++){
          size_t row = (size_t)(r0 + wr + fi*16 + (lane>>4)*4 + r);
          float v = acc[fi][fj][r];
          if (isz) v = v / (1.f + __expf(-v));   // pre-apply silu to z
          dst[row*256 + cc] = f2bf(v);
        }
      }
    }
  }
}

// ------- conv + silu (vectorized: 4 rows x 8 channels per thread) ----------
__global__ __launch_bounds__(256) void k_conv_silu(const bf16* __restrict__ xi,
      const float* __restrict__ cw, const float* __restrict__ cb,
      bf16* __restrict__ xc){
  int gid = blockIdx.x*256 + threadIdx.x;
  int dg  = gid & 31;
  int rg  = gid >> 5;
  const int r0 = rg*4;
  const int t0 = r0 % S_;
  const int d0 = dg*8;

  uint4 w[7];
  const uint4 z4 = make_uint4(0,0,0,0);
  #pragma unroll
  for (int i=0;i<7;i++){
    int off = i - 3;
    if (t0 == 0 && i < 3) w[i] = z4;
    else w[i] = *(const uint4*)(xi + (size_t)(r0+off)*256 + d0);
  }
  float f[7][8];
  #pragma unroll
  for (int i=0;i<7;i++){
    unsigned int ww[4] = {w[i].x, w[i].y, w[i].z, w[i].w};
    #pragma unroll
    for (int p=0;p<4;p++){
      f[i][p*2+0] = uphalf((unsigned short)(ww[p] & 0xffffu));
      f[i][p*2+1] = uphalf((unsigned short)(ww[p] >> 16));
    }
  }
  float wt[8][4], bias[8];
  #pragma unroll
  for (int c2=0;c2<2;c2++){
    float4 b4 = *(const float4*)(cb + d0 + c2*4);
    bias[c2*4+0]=b4.x; bias[c2*4+1]=b4.y; bias[c2*4+2]=b4.z; bias[c2*4+3]=b4.w;
  }
  #pragma unroll
  for (int c=0;c<8;c++){
    float4 w4 = *(const float4*)(cw + (d0+c)*4);
    wt[c][0]=w4.x; wt[c][1]=w4.y; wt[c][2]=w4.z; wt[c][3]=w4.w;
  }
  #pragma unroll
  for (int k=0;k<4;k++){
    unsigned int owords[4];
    #pragma unroll
    for (int p=0;p<4;p++){
      float o2[2];
      #pragma unroll
      for (int h=0;h<2;h++){
        int c = p*2+h;
        float acc = bias[c];
        #pragma unroll
        for (int j=0;j<4;j++) acc = fmaf(wt[c][j], f[k+j][c], acc);
        float sig = 1.f/(1.f + __expf(-acc));
        o2[h] = acc*sig;
      }
      owords[p] = pk2(o2[0], o2[1]);
    }
    uint4 outv = make_uint4(owords[0],owords[1],owords[2],owords[3]);
    *(uint4*)(xc + (size_t)(r0+k)*256 + d0) = outv;
  }
}

// -- gemm_x+dt (MFMA): xdbl = xc@Wx; BC[row][32]=B|C; dtb=softplus(dbl@Wdt+b)
__global__ __launch_bounds__(256) void k_gemm_x_dt_mfma(const bf16* __restrict__ xc,
      const bf16* __restrict__ Wxt, const float* __restrict__ Wdt, const float* __restrict__ bdt,
      float* __restrict__ BC, bf16* __restrict__ dtb){
  __shared__ __align__(16) unsigned short a_sh[64][136];
  __shared__ __align__(16) unsigned short b_sh[48][136];
  __shared__ __align__(16) float s_dbl[64][8];
  const int r0 = blockIdx.x*64;              // 1344 blocks
  const int tid = threadIdx.x;
  const int lane = tid & 63, wv = tid >> 6;
  const int fr = lane & 15, fk = (lane>>4)*8;
  const f32x4 zero = {0.f,0.f,0.f,0.f};
  f32x4 acc[3] = {zero,zero,zero};

  for (int kst=0;kst<2;kst++){
    if (kst) __syncthreads();
    #pragma unroll
    for (int q=0;q<4;q++){
      int fid = tid + 256*q;
      int r = fid >> 4, g = fid & 15;
      *(uint4*)&a_sh[r][g*8] = *(const uint4*)(xc + (size_t)(r0+r)*256 + kst*128 + g*8);
      if (fid < 768)
        *(uint4*)&b_sh[r][g*8] = *(const uint4*)(Wxt + (size_t)r*256 + kst*128 + g*8);
    }
    __syncthreads();
    #pragma unroll
    for (int ks=0;ks<4;ks++){
      bf16x8 a0 = *(const bf16x8*)&a_sh[wv*16+fr][ks*32+fk];
      #pragma unroll
      for (int fj=0;fj<3;fj++){
        bf16x8 bb = *(const bf16x8*)&b_sh[fj*16+fr][ks*32+fk];
        acc[fj] = MFMA16(a0,bb,acc[fj]);
      }
    }
  }
  #pragma unroll
  for (int fj=0;fj<3;fj++){
    int col = fj*16 + fr;
    #pragma unroll
    for (int r=0;r<4;r++){
      int rr = wv*16 + (lane>>4)*4 + r;
      size_t row = (size_t)(r0 + rr);
      if (col < 8)       s_dbl[rr][col] = acc[fj][r];
      else if (col < 40) BC[row*32 + (col-8)] = acc[fj][r];
    }
  }
  __syncthreads();
  float wdt[8];
  #pragma unroll
  for (int j=0;j<8;j++) wdt[j] = Wdt[j*256 + tid];
  float bd = bdt[tid];
  #pragma unroll
  for (int r=0;r<64;r++){
    float4 d0 = *(const float4*)&s_dbl[r][0];
    float4 d1 = *(const float4*)&s_dbl[r][4];
    float v = bd;
    v = fmaf(d0.x, wdt[0], v);
    v = fmaf(d0.y, wdt[1], v);
    v = fmaf(d0.z, wdt[2], v);
    v = fmaf(d0.w, wdt[3], v);
    v = fmaf(d1.x, wdt[4], v);
    v = fmaf(d1.y, wdt[5], v);
    v = fmaf(d1.z, wdt[6], v);
    v = fmaf(d1.w, wdt[7], v);
    float sp = (v > 20.f) ? v : __logf(1.f + __expf(v));
    dtb[(size_t)(r0+r)*256 + tid] = f2bf(sp);
  }
}

// ==== chunked scan (2 channels/thread, packed fp32) =========================
__device__ __forceinline__ bool load_A(const float* Alog, int d, f32x2 anl2[8]){
  const float4* ap = (const float4*)(Alog + d*16);
  float4 a0=ap[0], a1=ap[1], a2=ap[2], a3=ap[3];
  float tmp[16] = {a0.x,a0.y,a0.z,a0.w, a1.x,a1.y,a1.z,a1.w,
                   a2.x,a2.y,a2.z,a2.w, a3.x,a3.y,a3.z,a3.w};
  bool ok = true;
  #pragma unroll
  for (int n=0;n<16;n++) ok = ok && (fabsf(tmp[n] - LOGN[n]) < 1e-4f);
  if (!ok){
    #pragma unroll
    for (int i=0;i<8;i++){
      anl2[i].x = -__expf(tmp[i*2+0]) * 1.44269504f;
      anl2[i].y = -__expf(tmp[i*2+1]) * 1.44269504f;
    }
  }
  return ok;
}

__device__ __forceinline__ void unpackBC(const float4 v[4], f32x2 o[8]){
  o[0].x=v[0].x; o[0].y=v[0].y;  o[1].x=v[0].z; o[1].y=v[0].w;
  o[2].x=v[1].x; o[2].y=v[1].y;  o[3].x=v[1].z; o[3].y=v[1].w;
  o[4].x=v[2].x; o[4].y=v[2].y;  o[5].x=v[2].z; o[5].y=v[2].w;
  o[6].x=v[3].x; o[6].y=v[3].y;  o[7].x=v[3].z; o[7].y=v[3].w;
}

template<int CL>
__global__ __launch_bounds__(128) void k_scan_p1(const bf16* __restrict__ xc,
      const bf16* __restrict__ dtb, const float* __restrict__ BC,
      const float* __restrict__ Alog,
      float* __restrict__ hend, float* __restrict__ sumdt, int nc, int cl_rt){
  const int blk = blockIdx.x;
  const int b = blk / nc;
  const int c = blk - b*nc;
  const int d0 = threadIdx.x*2;
  const int cl = CL ? CL : cl_rt;
  f32x2 anlA[8], anlB[8];
  const bool okA = load_A(Alog, d0,   anlA);
  const bool okB = load_A(Alog, d0+1, anlB);
  f32x2 hA[8], hB[8];
  #pragma unroll
  for (int i=0;i<8;i++){ hA[i].x=0.f; hA[i].y=0.f; hB[i].x=0.f; hB[i].y=0.f; }
  float sA = 0.f, sB = 0.f;
  const size_t rowbase = (size_t)b*S_ + (size_t)c*cl;
  #pragma unroll 2
  for (int t=0;t<cl;t++){
    size_t row = rowbase + t;
    unsigned int dtp = *(const unsigned int*)(dtb + row*256 + d0);
    unsigned int up  = *(const unsigned int*)(xc  + row*256 + d0);
    float dtA = uphalf((unsigned short)(dtp & 0xffffu));
    float dtB = uphalf((unsigned short)(dtp >> 16));
    float uA  = uphalf((unsigned short)(up  & 0xffffu));
    float uB  = uphalf((unsigned short)(up  >> 16));
    sA += dtA; sB += dtB;
    const float4* bp = (const float4*)(BC + row*32);
    float4 Bv[4] = {bp[0], bp[1], bp[2], bp[3]};
    f32x2 B2[8];
    unpackBC(Bv, B2);
    f32x2 duA; duA.x = dtA*uA; duA.y = dtA*uA;
    f32x2 duB; duB.x = dtB*uB; duB.y = dtB*uB;
    f32x2 dAA[8], dAB[8];
    comp_dA2(dAA, dtA, okA, anlA);
    comp_dA2(dAB, dtB, okB, anlB);
    #pragma unroll
    for (int i=0;i<8;i++){
      hA[i] = dAA[i]*hA[i] + duA*B2[i];
      hB[i] = dAB[i]*hB[i] + duB*B2[i];
    }
  }
  float4* hp = (float4*)(hend + ((size_t)blk*256 + d0)*16);
  hp[0] = make_float4(hA[0].x,hA[0].y,hA[1].x,hA[1].y);
  hp[1] = make_float4(hA[2].x,hA[2].y,hA[3].x,hA[3].y);
  hp[2] = make_float4(hA[4].x,hA[4].y,hA[5].x,hA[5].y);
  hp[3] = make_float4(hA[6].x,hA[6].y,hA[7].x,hA[7].y);
  hp[4] = make_float4(hB[0].x,hB[0].y,hB[1].x,hB[1].y);
  hp[5] = make_float4(hB[2].x,hB[2].y,hB[3].x,hB[3].y);
  hp[6] = make_float4(hB[4].x,hB[4].y,hB[5].x,hB[5].y);
  hp[7] = make_float4(hB[6].x,hB[6].y,hB[7].x,hB[7].y);
  *(float2*)(sumdt + (size_t)blk*256 + d0) = make_float2(sA, sB);
}

// --- combine: one (b,d,n) scalar chain per thread; 512 blocks --------------
__global__ __launch_bounds__(256) void k_scan_comb(const float* __restrict__ Alog,
      const float* __restrict__ sumdt, float* __restrict__ hend, int nc){
  const int blk = blockIdx.x;
  const int b  = blk >> 4;
  const int dg = blk & 15;
  const int tid = threadIdx.x;
  const int dl = tid >> 4;
  const int n  = tid & 15;
  const int d  = dg*16 + dl;
  const float anl2 = -__expf(Alog[d*16 + n]) * 1.44269504f;
  float carry = 0.f;
  const size_t basei = (size_t)b*nc;
  for (int c=0;c<nc;c++){
    size_t blkc = basei + c;
    size_t hidx = (blkc*256 + d)*16 + n;
    float he  = hend[hidx];
    float sdt = sumdt[blkc*256 + d];
    hend[hidx] = carry;
    carry = fmaf(exp2f(sdt*anl2), carry, he);
  }
}

template<int CL>
__global__ __launch_bounds__(128) void k_scan_p2(const bf16* __restrict__ xcin,
      const bf16* __restrict__ dtb, const float* __restrict__ BC,
      const bf16* __restrict__ zg, const float* __restrict__ Alog,
      const float* __restrict__ Dpar, const float* __restrict__ hend,
      bf16* __restrict__ ym, int nc, int cl_rt){
  const int blk = blockIdx.x;
  const int b = blk / nc;
  const int c = blk - b*nc;
  const int d0 = threadIdx.x*2;
  const int cl = CL ? CL : cl_rt;
  f32x2 anlA[8], anlB[8];
  const bool okA = load_A(Alog, d0,   anlA);
  const bool okB = load_A(Alog, d0+1, anlB);
  float2 Dp2 = *(const float2*)(Dpar + d0);
  f32x2 hA[8], hB[8];
  {
    const float4* hp = (const float4*)(hend + ((size_t)blk*256 + d0)*16);
    float4 v0=hp[0], v1=hp[1], v2=hp[2], v3=hp[3];
    float4 v4=hp[4], v5=hp[5], v6=hp[6], v7=hp[7];
    hA[0].x=v0.x; hA[0].y=v0.y;  hA[1].x=v0.z; hA[1].y=v0.w;
    hA[2].x=v1.x; hA[2].y=v1.y;  hA[3].x=v1.z; hA[3].y=v1.w;
    hA[4].x=v2.x; hA[4].y=v2.y;  hA[5].x=v2.z; hA[5].y=v2.w;
    hA[6].x=v3.x; hA[6].y=v3.y;  hA[7].x=v3.z; hA[7].y=v3.w;
    hB[0].x=v4.x; hB[0].y=v4.y;  hB[1].x=v4.z; hB[1].y=v4.w;
    hB[2].x=v5.x; hB[2].y=v5.y;  hB[3].x=v5.z; hB[3].y=v5.w;
    hB[4].x=v6.x; hB[4].y=v6.y;  hB[5].x=v6.z; hB[5].y=v6.w;
    hB[6].x=v7.x; hB[6].y=v7.y;  hB[7].x=v7.z; hB[7].y=v7.w;
  }
  const size_t rowbase = (size_t)b*S_ + (size_t)c*cl;
  #pragma unroll 2
  for (int t=0;t<cl;t++){
    size_t row = rowbase + t;
    unsigned int dtp = *(const unsigned int*)(dtb  + row*256 + d0);
    unsigned int up  = *(const unsigned int*)(xcin + row*256 + d0);
    unsigned int gp  = *(const unsigned int*)(zg   + row*256 + d0);
    float dtA = uphalf((unsigned short)(dtp & 0xffffu));
    float dtB = uphalf((unsigned short)(dtp >> 16));
    float uA  = uphalf((unsigned short)(up  & 0xffffu));
    float uB  = uphalf((unsigned short)(up  >> 16));
    const float4* bp = (const float4*)(BC + row*32);
    float4 Bv[4] = {bp[0], bp[1], bp[2], bp[3]};
    float4 Cv[4] = {bp[4], bp[5], bp[6], bp[7]};
    f32x2 B2[8], C2[8];
    unpackBC(Bv, B2);
    unpackBC(Cv, C2);
    f32x2 duA; duA.x = dtA*uA; duA.y = dtA*uA;
    f32x2 duB; duB.x = dtB*uB; duB.y = dtB*uB;
    f32x2 dAA[8], dAB[8];
    comp_dA2(dAA, dtA, okA, anlA);
    comp_dA2(dAB, dtB, okB, anlB);
    f32x2 accA; accA.x=0.f; accA.y=0.f;
    f32x2 accB; accB.x=0.f; accB.y=0.f;
    #pragma unroll
    for (int i=0;i<8;i++){
      hA[i] = dAA[i]*hA[i] + duA*B2[i];
      hB[i] = dAB[i]*hB[i] + duB*B2[i];
      accA = accA + hA[i]*C2[i];
      accB = accB + hB[i]*C2[i];
    }
    float pA = accA.x + accA.y;
    float pB = accB.x + accB.y;
    float yA = fmaf(uA, Dp2.x, pA);
    float yB = fmaf(uB, Dp2.y, pB);
    float gA = uphalf((unsigned short)(gp & 0xffffu));   // silu pre-applied
    float gB = uphalf((unsigned short)(gp >> 16));
    *(unsigned int*)(ym + row*256 + d0) = pk2(yA*gA, yB*gB);
  }
}

// ------- gemm_out (MFMA): dx = ym @ W_out (K=256), fwd/bwd-fold ------------
__global__ __launch_bounds__(256) void k_gemm_out_mfma(const bf16* __restrict__ ym,
      const bf16* __restrict__ Wt, bf16* __restrict__ dx, int rev){
  __shared__ __align__(16) unsigned short a_sh[64][136];
  __shared__ __align__(16) unsigned short b_sh[64][136];
  const int blk = blockIdx.x;                // 1344 * 2
  const int bm = blk >> 1, bn = blk & 1;
  const int r0 = bm*64, n0 = bn*64;
  const int b  = r0 / S_;
  const int t0 = r0 - b*S_;
  const int tid = threadIdx.x;
  const int lane = tid & 63, wv = tid >> 6;
  const int wr = (wv>>1)*32, wc = (wv&1)*32;
  const int fr = lane & 15, fk = (lane>>4)*8;
  const f32x4 zero = {0.f,0.f,0.f,0.f};
  f32x4 acc[2][2] = {{zero,zero},{zero,zero}};

  for (int kst=0;kst<2;kst++){
    if (kst) __syncthreads();
    #pragma unroll
    for (int q=0;q<4;q++){
      int fid = tid + 256*q;
      int r = fid >> 4, g = fid & 15;
      *(uint4*)&a_sh[r][g*8] = *(const uint4*)(ym + (size_t)(r0+r)*256 + kst*128 + g*8);
      *(uint4*)&b_sh[r][g*8] = *(const uint4*)(Wt + (size_t)(n0+r)*256 + kst*128 + g*8);
    }
    __syncthreads();
    #pragma unroll
    for (int ks=0;ks<4;ks++){
      bf16x8 a0 = *(const bf16x8*)&a_sh[wr+fr   ][ks*32+fk];
      bf16x8 a1 = *(const bf16x8*)&a_sh[wr+16+fr][ks*32+fk];
      bf16x8 b0 = *(const bf16x8*)&b_sh[wc+fr   ][ks*32+fk];
      bf16x8 b1 = *(const bf16x8*)&b_sh[wc+16+fr][ks*32+fk];
      acc[0][0] = MFMA16(a0,b0,acc[0][0]);
      acc[0][1] = MFMA16(a0,b1,acc[0][1]);
      acc[1][0] = MFMA16(a1,b0,acc[1][0]);
      acc[1][1] = MFMA16(a1,b1,acc[1][1]);
    }
  }
  #pragma unroll
  for (int fi=0;fi<2;fi++){
    #pragma unroll
    for (int fj=0;fj<2;fj++){
      int c = n0 + wc + fj*16 + fr;
      #pragma unroll
      for (int r=0;r<4;r++){
        int t = t0 + wr + fi*16 + (lane>>4)*4 + r;
        size_t drow = (size_t)b*S_ + (rev ? (S_-1 - t) : t);
        if (rev){
          float old = bf2f(dx[drow*128 + c]);
          dx[drow*128 + c] = f2bf(old + 0.5f*acc[fi][fj][r]);
        } else {
          dx[drow*128 + c] = f2bf(0.5f*acc[fi][fj][r]);
        }
      }
    }
  }
}

// --- combine + layernorm + residual (vectorized: 4 ch/lane, 2 rows/wave) ---
__global__ __launch_bounds__(256) void k_combine_ln(const bf16* __restrict__ dx,
      const float* __restrict__ lnw, const float* __restrict__ lnb,
      float* __restrict__ x){
  const int tid  = threadIdx.x;
  const int wv   = tid >> 6;
  const int lane = tid & 63;
  const int row  = blockIdx.x*8 + wv*2 + (lane >> 5);
  const int c0   = (lane & 31)*4;
  ushort4 d4 = *(const ushort4*)(dx + (size_t)row*128 + c0);
  float v0 = uphalf(d4.x), v1 = uphalf(d4.y), v2 = uphalf(d4.z), v3 = uphalf(d4.w);
  float s = (v0+v1)+(v2+v3);
  #pragma unroll
  for (int m=1;m<32;m<<=1) s += __shfl_xor(s, m);
  float mu = s * (1.f/128.f);
  float e0 = v0-mu, e1 = v1-mu, e2 = v2-mu, e3 = v3-mu;
  float q = (e0*e0+e1*e1)+(e2*e2+e3*e3);
  #pragma unroll
  for (int m=1;m<32;m<<=1) q += __shfl_xor(q, m);
  float rs = rsqrtf(q*(1.f/128.f) + 1e-5f);
  float4 w4 = *(const float4*)(lnw + c0);
  float4 b4 = *(const float4*)(lnb + c0);
  float4 xv = *(float4*)(x + (size_t)row*128 + c0);
  xv.x += e0*rs*w4.x + b4.x;
  xv.y += e1*rs*w4.y + b4.y;
  xv.z += e2*rs*w4.z + b4.z;
  xv.w += e3*rs*w4.w + b4.w;
  *(float4*)(x + (size_t)row*128 + c0) = xv;
}

// ---------------- pyramid gather ----------------
__global__ void k_pyramid(const float* __restrict__ x, float* __restrict__ out){
  int idx = blockIdx.x*256 + threadIdx.x;
  int j = idx & 31;
  int i = (idx >> 5) & 31;
  int c = (idx >> 10) & 127;
  int m = (idx >> 17) & 31;
  int o = idx >> 22;
  int base = o*1344;
  size_t xm = ((size_t)m * S_ + base) * 128 + c;
  float v = x[xm + (size_t)(320 + i*32 + j)*128]
          + x[xm + (size_t)(64 + (i>>1)*16 + (j>>1))*128]
          + x[xm + (size_t)((i>>2)*8 + (j>>2))*128];
  out[idx] = v;
}

extern "C" void kernel_launch(void* const* d_in, const int* in_sizes, int n_in,
                              void* d_out, int out_size, void* d_ws, size_t ws_size,
                              hipStream_t stream){
  const float* f0   = (const float*)d_in[0];
  const float* f1   = (const float*)d_in[1];
  const float* W_in = (const float*)d_in[2];
  const float* cw   = (const float*)d_in[3];
  const float* cb   = (const float*)d_in[4];
  const float* Wx   = (const float*)d_in[5];
  const float* Wdt  = (const float*)d_in[6];
  const float* bdt  = (const float*)d_in[7];
  const float* Alog = (const float*)d_in[8];
  const float* Dpar = (const float*)d_in[9];
  const float* Wout = (const float*)d_in[10];
  const float* lnw  = (const float*)d_in[11];
  const float* lnb  = (const float*)d_in[12];

  const size_t base = 214695936;
  int nc = 0;
  const int cand[6] = {84,42,21,12,6,2};
  for (int i=0;i<6;i++){
    size_t need = base + (size_t)32*cand[i]*256*16*4;
    if (ws_size >= need){ nc = cand[i]; break; }
  }
  if (nc == 0) return;
  const int cl = S_/nc;

  char* ws = (char*)d_ws;
  float* x      = (float*)(ws + 0);
  bf16*  xi     = (bf16*) (ws + 44040192);
  bf16*  dtb    = (bf16*) (ws + 44040192);
  bf16*  z      = (bf16*) (ws + 88080384);
  bf16*  xc     = (bf16*) (ws + 132120576);
  float* BC     = (float*)(ws + 176160768);
  float* sumdt  = (float*)(ws + 187170816);
  bf16*  Wt_in  = (bf16*) (ws + 189923328);
  bf16*  Wt_out = (bf16*) (ws + 190447616);
  bf16*  Wxt    = (bf16*) (ws + 190709760);
  bf16*  dx     = (bf16*) (ws + 192675840);
  float* hend   = (float*)(ws + 214695936);

  k_init_x<<<43008,256,0,stream>>>(f0, f1, x);
  k_wconv <<<1728,256,0,stream>>>(W_in, Wx, Wout, Wt_in, Wxt, Wt_out);

  for (int l=0;l<2;l++){
    for (int r=0;r<2;r++){
      int lr = l*2 + r;
      const float* Al = Alog + (size_t)lr*256*16;
      k_gemm_in_mfma  <<<1344,256,0,stream>>>(x, Wt_in + (size_t)lr*65536, xi, z, r);
      k_conv_silu     <<<2688,256,0,stream>>>(xi, cw + lr*256*4, cb + lr*256, xc);
      k_gemm_x_dt_mfma<<<1344,256,0,stream>>>(xc, Wxt + (size_t)lr*12288,
                                              Wdt + (size_t)lr*8*256, bdt + lr*256, BC, dtb);
      if (cl == 32)
        k_scan_p1<32><<<32*nc,128,0,stream>>>(xc, dtb, BC, Al, hend, sumdt, nc, cl);
      else if (cl == 64)
        k_scan_p1<64><<<32*nc,128,0,stream>>>(xc, dtb, BC, Al, hend, sumdt, nc, cl);
      else
        k_scan_p1<0> <<<32*nc,128,0,stream>>>(xc, dtb, BC, Al, hend, sumdt, nc, cl);
      k_scan_comb<<<512,256,0,stream>>>(Al, sumdt, hend, nc);
      if (cl == 32)
        k_scan_p2<32><<<32*nc,128,0,stream>>>(xc, dtb, BC, z, Al, Dpar + lr*256,
                                              hend, xc, nc, cl);
      else if (cl == 64)
        k_scan_p2<64><<<32*nc,128,0,stream>>>(xc, dtb, BC, z, Al, Dpar + lr*256,
                                              hend, xc, nc, cl);
      else
        k_scan_p2<0> <<<32*nc,128,0,stream>>>(xc, dtb, BC, z, Al, Dpar + lr*256,
                                              hend, xc, nc, cl);
      k_gemm_out_mfma <<<2688,256,0,stream>>>(xc, Wt_out + (size_t)lr*32768, dx, r);
    }
    k_combine_ln<<<10752,256,0,stream>>>(dx, lnw + l*128, lnb + l*128, x);
  }

  k_pyramid<<<32768,256,0,stream>>>(x, (float*)d_out);
}

// Round 21
// 1064.749 us; speedup vs baseline: 1.1695x; 1.0474x over previous
//
#include <hip/hip_runtime.h>
#include <hip/hip_bf16.h>
#include <math.h>

#define B_   32
#define S_   2688
#define D_   128
#define DI_  256
#define DS_  16
#define NROWS (B_*S_)   // 86016

typedef __hip_bfloat16 bf16;
typedef float f32x4 __attribute__((ext_vector_type(4)));
typedef float f32x2 __attribute__((ext_vector_type(2)));
typedef short bf16x8 __attribute__((ext_vector_type(8)));
#define MFMA16(a,b,c) __builtin_amdgcn_mfma_f32_16x16x32_bf16(a,b,c,0,0,0)

__device__ __forceinline__ float bf2f(bf16 v){ return __bfloat162float(v); }
__device__ __forceinline__ bf16  f2bf(float f){ return __float2bfloat16(f); }
__device__ __forceinline__ float uphalf(unsigned short u){
  union { unsigned int i; float f; } c; c.i = ((unsigned int)u) << 16; return c.f;
}
__device__ __forceinline__ unsigned int pk2(float a, float b){
  unsigned int lo = __hip_bfloat16_raw(f2bf(a)).x;
  unsigned int hi = __hip_bfloat16_raw(f2bf(b)).x;
  return lo | (hi << 16);
}

// log(n+1) fp32 constants for the A_log pattern check.
__device__ __constant__ float LOGN[16] = {
  0.0f, 0.69314718056f, 1.09861228867f, 1.38629436112f,
  1.60943791243f, 1.79175946923f, 1.94591014906f, 2.07944154168f,
  2.19722457734f, 2.30258509299f, 2.39789527280f, 2.48490664979f,
  2.56494935746f, 2.63905732962f, 2.70805020110f, 2.77258872224f };

// dA2[i] = {exp(dt*A_{2i}), exp(dt*A_{2i+1})}.
// Fast path (ok): A_n = -(n+1) => dA = w^(n+1), w=exp(-dt); packed chain *w^2.
__device__ __forceinline__ void comp_dA2(f32x2 dA2[8], float dtv, bool ok,
                                         const f32x2 anl2[8]){
  if (ok){
    float w1 = __expf(-dtv);
    float w2 = w1*w1;
    f32x2 ww; ww.x = w2; ww.y = w2;
    dA2[0].x = w1; dA2[0].y = w2;
    #pragma unroll
    for (int i=1;i<8;i++) dA2[i] = dA2[i-1]*ww;
  } else {
    #pragma unroll
    for (int i=0;i<8;i++){
      dA2[i].x = exp2f(dtv*anl2[i].x);
      dA2[i].y = exp2f(dtv*anl2[i].y);
    }
  }
}

__device__ __forceinline__ bool load_A(const float* Alog, int d, f32x2 anl2[8]){
  const float4* ap = (const float4*)(Alog + d*16);
  float4 a0=ap[0], a1=ap[1], a2=ap[2], a3=ap[3];
  float tmp[16] = {a0.x,a0.y,a0.z,a0.w, a1.x,a1.y,a1.z,a1.w,
                   a2.x,a2.y,a2.z,a2.w, a3.x,a3.y,a3.z,a3.w};
  bool ok = true;
  #pragma unroll
  for (int n=0;n<16;n++) ok = ok && (fabsf(tmp[n] - LOGN[n]) < 1e-4f);
  if (!ok){
    #pragma unroll
    for (int i=0;i<8;i++){
      anl2[i].x = -__expf(tmp[i*2+0]) * 1.44269504f;
      anl2[i].y = -__expf(tmp[i*2+1]) * 1.44269504f;
    }
  }
  return ok;
}

__device__ __forceinline__ void unpackBC(const float4 v[4], f32x2 o[8]){
  o[0].x=v[0].x; o[0].y=v[0].y;  o[1].x=v[0].z; o[1].y=v[0].w;
  o[2].x=v[1].x; o[2].y=v[1].y;  o[3].x=v[1].z; o[3].y=v[1].w;
  o[4].x=v[2].x; o[4].y=v[2].y;  o[5].x=v[2].z; o[5].y=v[2].w;
  o[6].x=v[3].x; o[6].y=v[3].y;  o[7].x=v[3].z; o[7].y=v[3].w;
}

// ---------------- init: x = concat(feat0, feat1) along seq ----------------
__global__ void k_init_x(const float* __restrict__ f0, const float* __restrict__ f1,
                         float* __restrict__ x){
  int idx = blockIdx.x*256 + threadIdx.x;
  if (idx >= B_*S_*D_) return;
  const int per_b = S_*D_;
  const int half  = 1344*D_;
  int b = idx / per_b;
  int rem = idx - b*per_b;
  x[idx] = (rem < half) ? f0[b*half + rem] : f1[b*half + rem - half];
}

// -------- weight convert/transpose to bf16 ---------------------------------
__global__ void k_wconv(const float* __restrict__ W_in, const float* __restrict__ Wx,
                        const float* __restrict__ W_out,
                        bf16* __restrict__ Wt_in, bf16* __restrict__ Wxt,
                        bf16* __restrict__ Wt_out){
  int idx = blockIdx.x*256 + threadIdx.x;   // 1728*256 = 442368
  if (idx < 262144){
    int k = idx & 127, n = (idx>>7) & 511, lr = idx>>16;
    Wt_in[idx] = f2bf(W_in[((size_t)lr*128 + k)*512 + n]);
    return;
  }
  int i2 = idx - 262144;
  if (i2 < 131072){
    int k = i2 & 255, n = (i2>>8) & 127, lr = i2>>15;
    Wt_out[i2] = f2bf(W_out[((size_t)lr*256 + k)*128 + n]);
    return;
  }
  int i3 = i2 - 131072;
  if (i3 < 49152){
    int k = i3 & 255, nn = i3>>8, n = nn % 48, lr = nn / 48;
    Wxt[i3] = (n < 40) ? f2bf(Wx[((size_t)lr*256 + k)*40 + n]) : f2bf(0.f);
  }
}

// --- gemm_in (MFMA): [xi|z] = x(_rev) @ W_in; z half stored as silu(z) -----
__global__ __launch_bounds__(256) void k_gemm_in_mfma(const float* __restrict__ x,
      const bf16* __restrict__ Wt, bf16* __restrict__ xi, bf16* __restrict__ z, int rev){
  __shared__ __align__(16) unsigned short a_sh[64][136];
  __shared__ __align__(16) unsigned short b_sh[64][136];
  const int r0 = blockIdx.x*64;              // 1344 blocks
  const int b  = r0 / S_;
  const int t0 = r0 - b*S_;
  const int tid = threadIdx.x;
  const int lane = tid & 63, wv = tid >> 6;
  const int wr = (wv>>1)*32, wc = (wv&1)*32;
  const int fr = lane & 15, fk = (lane>>4)*8;

  #pragma unroll
  for (int q=0;q<4;q++){
    int fid = tid + 256*q;
    int r = fid >> 4, g = fid & 15;
    int t = t0 + r;
    int rg = b*S_ + (rev ? (S_-1 - t) : t);
    const float* src = x + (size_t)rg*128 + g*8;
    float4 v0 = *(const float4*)(src);
    float4 v1 = *(const float4*)(src + 4);
    uint4 pk;
    pk.x = pk2(v0.x, v0.y);
    pk.y = pk2(v0.z, v0.w);
    pk.z = pk2(v1.x, v1.y);
    pk.w = pk2(v1.z, v1.w);
    *(uint4*)&a_sh[r][g*8] = pk;
    *(uint4*)&b_sh[r][g*8] = *(const uint4*)(Wt + (size_t)r*128 + g*8);
  }
  __syncthreads();

  for (int bn=0;bn<8;bn++){
    if (bn){
      __syncthreads();
      #pragma unroll
      for (int q=0;q<4;q++){
        int fid = tid + 256*q;
        int r = fid >> 4, g = fid & 15;
        *(uint4*)&b_sh[r][g*8] = *(const uint4*)(Wt + (size_t)(bn*64+r)*128 + g*8);
      }
      __syncthreads();
    }
    const f32x4 zero = {0.f,0.f,0.f,0.f};
    f32x4 acc[2][2] = {{zero,zero},{zero,zero}};
    #pragma unroll
    for (int ks=0;ks<4;ks++){
      bf16x8 a0 = *(const bf16x8*)&a_sh[wr+fr   ][ks*32+fk];
      bf16x8 a1 = *(const bf16x8*)&a_sh[wr+16+fr][ks*32+fk];
      bf16x8 b0 = *(const bf16x8*)&b_sh[wc+fr   ][ks*32+fk];
      bf16x8 b1 = *(const bf16x8*)&b_sh[wc+16+fr][ks*32+fk];
      acc[0][0] = MFMA16(a0,b0,acc[0][0]);
      acc[0][1] = MFMA16(a0,b1,acc[0][1]);
      acc[1][0] = MFMA16(a1,b0,acc[1][0]);
      acc[1][1] = MFMA16(a1,b1,acc[1][1]);
    }
    #pragma unroll
    for (int fi=0;fi<2;fi++){
      #pragma unroll
      for (int fj=0;fj<2;fj++){
        int gcol = bn*64 + wc + fj*16 + fr;
        bool isz = (gcol >= 256);
        bf16* dst = isz ? z : xi;
        int cc = gcol & 255;
        #pragma unroll
        for (int r=0;r<4;r++){
          size_t row = (size_t)(r0 + wr + fi*16 + (lane>>4)*4 + r);
          float v = acc[fi][fj][r];
          if (isz) v = v / (1.f + __expf(-v));   // pre-apply silu to z
          dst[row*256 + cc] = f2bf(v);
        }
      }
    }
  }
}

// ------- conv + silu (vectorized: 4 rows x 8 channels per thread) ----------
__global__ __launch_bounds__(256) void k_conv_silu(const bf16* __restrict__ xi,
      const float* __restrict__ cw, const float* __restrict__ cb,
      bf16* __restrict__ xc){
  int gid = blockIdx.x*256 + threadIdx.x;
  int dg  = gid & 31;
  int rg  = gid >> 5;
  const int r0 = rg*4;
  const int t0 = r0 % S_;
  const int d0 = dg*8;

  uint4 w[7];
  const uint4 z4 = make_uint4(0,0,0,0);
  #pragma unroll
  for (int i=0;i<7;i++){
    int off = i - 3;
    if (t0 == 0 && i < 3) w[i] = z4;
    else w[i] = *(const uint4*)(xi + (size_t)(r0+off)*256 + d0);
  }
  float f[7][8];
  #pragma unroll
  for (int i=0;i<7;i++){
    unsigned int ww[4] = {w[i].x, w[i].y, w[i].z, w[i].w};
    #pragma unroll
    for (int p=0;p<4;p++){
      f[i][p*2+0] = uphalf((unsigned short)(ww[p] & 0xffffu));
      f[i][p*2+1] = uphalf((unsigned short)(ww[p] >> 16));
    }
  }
  float wt[8][4], bias[8];
  #pragma unroll
  for (int c2=0;c2<2;c2++){
    float4 b4 = *(const float4*)(cb + d0 + c2*4);
    bias[c2*4+0]=b4.x; bias[c2*4+1]=b4.y; bias[c2*4+2]=b4.z; bias[c2*4+3]=b4.w;
  }
  #pragma unroll
  for (int c=0;c<8;c++){
    float4 w4 = *(const float4*)(cw + (d0+c)*4);
    wt[c][0]=w4.x; wt[c][1]=w4.y; wt[c][2]=w4.z; wt[c][3]=w4.w;
  }
  #pragma unroll
  for (int k=0;k<4;k++){
    unsigned int owords[4];
    #pragma unroll
    for (int p=0;p<4;p++){
      float o2[2];
      #pragma unroll
      for (int h=0;h<2;h++){
        int c = p*2+h;
        float acc = bias[c];
        #pragma unroll
        for (int j=0;j<4;j++) acc = fmaf(wt[c][j], f[k+j][c], acc);
        float sig = 1.f/(1.f + __expf(-acc));
        o2[h] = acc*sig;
      }
      owords[p] = pk2(o2[0], o2[1]);
    }
    uint4 outv = make_uint4(owords[0],owords[1],owords[2],owords[3]);
    *(uint4*)(xc + (size_t)(r0+k)*256 + d0) = outv;
  }
}

// == FUSED gemm_x + dt + scan_p1 (requires nc==84, cl==32: 64 rows = 2 chunks)
__global__ __launch_bounds__(256) void k_gemm_x_dt_scan(const bf16* __restrict__ xc,
      const bf16* __restrict__ Wxt, const float* __restrict__ Wdt, const float* __restrict__ bdt,
      float* __restrict__ BC, bf16* __restrict__ dtb, const float* __restrict__ Alog,
      float* __restrict__ hend, float* __restrict__ sumdt){
  __shared__ __align__(16) unsigned short a_sh[64][136];
  __shared__ __align__(16) unsigned short b_sh[48][136];
  __shared__ __align__(16) float s_dbl[64][8];
  __shared__ __align__(16) float s_bc[64][32];
  const int r0 = blockIdx.x*64;              // 1344 blocks
  const int tid = threadIdx.x;
  const int lane = tid & 63, wv = tid >> 6;
  const int fr = lane & 15, fk = (lane>>4)*8;
  const f32x4 zero = {0.f,0.f,0.f,0.f};
  f32x4 acc[3] = {zero,zero,zero};

  for (int kst=0;kst<2;kst++){
    if (kst) __syncthreads();
    #pragma unroll
    for (int q=0;q<4;q++){
      int fid = tid + 256*q;
      int r = fid >> 4, g = fid & 15;
      *(uint4*)&a_sh[r][g*8] = *(const uint4*)(xc + (size_t)(r0+r)*256 + kst*128 + g*8);
      if (fid < 768)
        *(uint4*)&b_sh[r][g*8] = *(const uint4*)(Wxt + (size_t)r*256 + kst*128 + g*8);
    }
    __syncthreads();
    #pragma unroll
    for (int ks=0;ks<4;ks++){
      bf16x8 a0 = *(const bf16x8*)&a_sh[wv*16+fr][ks*32+fk];
      #pragma unroll
      for (int fj=0;fj<3;fj++){
        bf16x8 bb = *(const bf16x8*)&b_sh[fj*16+fr][ks*32+fk];
        acc[fj] = MFMA16(a0,bb,acc[fj]);
      }
    }
  }
  #pragma unroll
  for (int fj=0;fj<3;fj++){
    int col = fj*16 + fr;
    #pragma unroll
    for (int r=0;r<4;r++){
      int rr = wv*16 + (lane>>4)*4 + r;
      size_t row = (size_t)(r0 + rr);
      if (col < 8)       s_dbl[rr][col] = acc[fj][r];
      else if (col < 40){
        BC[row*32 + (col-8)] = acc[fj][r];
        s_bc[rr][col-8] = acc[fj][r];
      }
    }
  }
  __syncthreads();

  // fused dt + chunk-local scan (channel d = tid; 2 chunks of 32 rows)
  const int d = tid;
  const int b = r0 / S_;
  const int t0 = r0 - b*S_;
  const size_t idx0 = (size_t)b*84 + (t0 >> 5);
  float wdt[8];
  #pragma unroll
  for (int j=0;j<8;j++) wdt[j] = Wdt[j*256 + d];
  float bd = bdt[d];
  f32x2 anl[8];
  const bool ok = load_A(Alog, d, anl);
  f32x2 h2[8];
  #pragma unroll
  for (int i=0;i<8;i++){ h2[i].x=0.f; h2[i].y=0.f; }
  float sdt = 0.f;
  for (int r=0;r<64;r++){
    float4 q0 = *(const float4*)&s_dbl[r][0];
    float4 q1 = *(const float4*)&s_dbl[r][4];
    float v = bd;
    v = fmaf(q0.x, wdt[0], v);
    v = fmaf(q0.y, wdt[1], v);
    v = fmaf(q0.z, wdt[2], v);
    v = fmaf(q0.w, wdt[3], v);
    v = fmaf(q1.x, wdt[4], v);
    v = fmaf(q1.y, wdt[5], v);
    v = fmaf(q1.z, wdt[6], v);
    v = fmaf(q1.w, wdt[7], v);
    float sp = (v > 20.f) ? v : __logf(1.f + __expf(v));
    bf16 spb = f2bf(sp);
    dtb[(size_t)(r0+r)*256 + d] = spb;
    float dtv = bf2f(spb);                  // bf16-rounded: matches scan_p2
    float u = bf2f(xc[(size_t)(r0+r)*256 + d]);
    sdt += dtv;
    f32x2 du2; du2.x = dtv*u; du2.y = dtv*u;
    const float4* bp = (const float4*)&s_bc[r][0];
    float4 Bv[4] = {bp[0], bp[1], bp[2], bp[3]};
    f32x2 B2[8];
    unpackBC(Bv, B2);
    f32x2 dA2[8];
    comp_dA2(dA2, dtv, ok, anl);
    #pragma unroll
    for (int i=0;i<8;i++)
      h2[i] = dA2[i]*h2[i] + du2*B2[i];
    if (r == 31){
      float4* hp = (float4*)(hend + (idx0*256 + d)*16);
      hp[0] = make_float4(h2[0].x,h2[0].y,h2[1].x,h2[1].y);
      hp[1] = make_float4(h2[2].x,h2[2].y,h2[3].x,h2[3].y);
      hp[2] = make_float4(h2[4].x,h2[4].y,h2[5].x,h2[5].y);
      hp[3] = make_float4(h2[6].x,h2[6].y,h2[7].x,h2[7].y);
      sumdt[idx0*256 + d] = sdt;
      #pragma unroll
      for (int i=0;i<8;i++){ h2[i].x=0.f; h2[i].y=0.f; }
      sdt = 0.f;
    }
  }
  float4* hp = (float4*)(hend + ((idx0+1)*256 + d)*16);
  hp[0] = make_float4(h2[0].x,h2[0].y,h2[1].x,h2[1].y);
  hp[1] = make_float4(h2[2].x,h2[2].y,h2[3].x,h2[3].y);
  hp[2] = make_float4(h2[4].x,h2[4].y,h2[5].x,h2[5].y);
  hp[3] = make_float4(h2[6].x,h2[6].y,h2[7].x,h2[7].y);
  sumdt[(idx0+1)*256 + d] = sdt;
}

// -- gemm_x+dt (MFMA) unfused fallback (nc != 84) ----------------------------
__global__ __launch_bounds__(256) void k_gemm_x_dt_mfma(const bf16* __restrict__ xc,
      const bf16* __restrict__ Wxt, const float* __restrict__ Wdt, const float* __restrict__ bdt,
      float* __restrict__ BC, bf16* __restrict__ dtb){
  __shared__ __align__(16) unsigned short a_sh[64][136];
  __shared__ __align__(16) unsigned short b_sh[48][136];
  __shared__ __align__(16) float s_dbl[64][8];
  const int r0 = blockIdx.x*64;
  const int tid = threadIdx.x;
  const int lane = tid & 63, wv = tid >> 6;
  const int fr = lane & 15, fk = (lane>>4)*8;
  const f32x4 zero = {0.f,0.f,0.f,0.f};
  f32x4 acc[3] = {zero,zero,zero};

  for (int kst=0;kst<2;kst++){
    if (kst) __syncthreads();
    #pragma unroll
    for (int q=0;q<4;q++){
      int fid = tid + 256*q;
      int r = fid >> 4, g = fid & 15;
      *(uint4*)&a_sh[r][g*8] = *(const uint4*)(xc + (size_t)(r0+r)*256 + kst*128 + g*8);
      if (fid < 768)
        *(uint4*)&b_sh[r][g*8] = *(const uint4*)(Wxt + (size_t)r*256 + kst*128 + g*8);
    }
    __syncthreads();
    #pragma unroll
    for (int ks=0;ks<4;ks++){
      bf16x8 a0 = *(const bf16x8*)&a_sh[wv*16+fr][ks*32+fk];
      #pragma unroll
      for (int fj=0;fj<3;fj++){
        bf16x8 bb = *(const bf16x8*)&b_sh[fj*16+fr][ks*32+fk];
        acc[fj] = MFMA16(a0,bb,acc[fj]);
      }
    }
  }
  #pragma unroll
  for (int fj=0;fj<3;fj++){
    int col = fj*16 + fr;
    #pragma unroll
    for (int r=0;r<4;r++){
      int rr = wv*16 + (lane>>4)*4 + r;
      size_t row = (size_t)(r0 + rr);
      if (col < 8)       s_dbl[rr][col] = acc[fj][r];
      else if (col < 40) BC[row*32 + (col-8)] = acc[fj][r];
    }
  }
  __syncthreads();
  float wdt[8];
  #pragma unroll
  for (int j=0;j<8;j++) wdt[j] = Wdt[j*256 + tid];
  float bd = bdt[tid];
  #pragma unroll
  for (int r=0;r<64;r++){
    float4 d0 = *(const float4*)&s_dbl[r][0];
    float4 d1 = *(const float4*)&s_dbl[r][4];
    float v = bd;
    v = fmaf(d0.x, wdt[0], v);
    v = fmaf(d0.y, wdt[1], v);
    v = fmaf(d0.z, wdt[2], v);
    v = fmaf(d0.w, wdt[3], v);
    v = fmaf(d1.x, wdt[4], v);
    v = fmaf(d1.y, wdt[5], v);
    v = fmaf(d1.z, wdt[6], v);
    v = fmaf(d1.w, wdt[7], v);
    float sp = (v > 20.f) ? v : __logf(1.f + __expf(v));
    dtb[(size_t)(r0+r)*256 + tid] = f2bf(sp);
  }
}

// ---- scan_p1 (fallback for nc != 84): 2 channels/thread, packed fp32 -------
__global__ __launch_bounds__(128) void k_scan_p1(const bf16* __restrict__ xc,
      const bf16* __restrict__ dtb, const float* __restrict__ BC,
      const float* __restrict__ Alog,
      float* __restrict__ hend, float* __restrict__ sumdt, int nc, int cl){
  const int blk = blockIdx.x;
  const int b = blk / nc;
  const int c = blk - b*nc;
  const int d0 = threadIdx.x*2;
  f32x2 anlA[8], anlB[8];
  const bool okA = load_A(Alog, d0,   anlA);
  const bool okB = load_A(Alog, d0+1, anlB);
  f32x2 hA[8], hB[8];
  #pragma unroll
  for (int i=0;i<8;i++){ hA[i].x=0.f; hA[i].y=0.f; hB[i].x=0.f; hB[i].y=0.f; }
  float sA = 0.f, sB = 0.f;
  const size_t rowbase = (size_t)b*S_ + (size_t)c*cl;
  for (int t=0;t<cl;t++){
    size_t row = rowbase + t;
    unsigned int dtp = *(const unsigned int*)(dtb + row*256 + d0);
    unsigned int up  = *(const unsigned int*)(xc  + row*256 + d0);
    float dtA = uphalf((unsigned short)(dtp & 0xffffu));
    float dtB = uphalf((unsigned short)(dtp >> 16));
    float uA  = uphalf((unsigned short)(up  & 0xffffu));
    float uB  = uphalf((unsigned short)(up  >> 16));
    sA += dtA; sB += dtB;
    const float4* bp = (const float4*)(BC + row*32);
    float4 Bv[4] = {bp[0], bp[1], bp[2], bp[3]};
    f32x2 B2[8];
    unpackBC(Bv, B2);
    f32x2 duA; duA.x = dtA*uA; duA.y = dtA*uA;
    f32x2 duB; duB.x = dtB*uB; duB.y = dtB*uB;
    f32x2 dAA[8], dAB[8];
    comp_dA2(dAA, dtA, okA, anlA);
    comp_dA2(dAB, dtB, okB, anlB);
    #pragma unroll
    for (int i=0;i<8;i++){
      hA[i] = dAA[i]*hA[i] + duA*B2[i];
      hB[i] = dAB[i]*hB[i] + duB*B2[i];
    }
  }
  float4* hp = (float4*)(hend + ((size_t)blk*256 + d0)*16);
  hp[0] = make_float4(hA[0].x,hA[0].y,hA[1].x,hA[1].y);
  hp[1] = make_float4(hA[2].x,hA[2].y,hA[3].x,hA[3].y);
  hp[2] = make_float4(hA[4].x,hA[4].y,hA[5].x,hA[5].y);
  hp[3] = make_float4(hA[6].x,hA[6].y,hA[7].x,hA[7].y);
  hp[4] = make_float4(hB[0].x,hB[0].y,hB[1].x,hB[1].y);
  hp[5] = make_float4(hB[2].x,hB[2].y,hB[3].x,hB[3].y);
  hp[6] = make_float4(hB[4].x,hB[4].y,hB[5].x,hB[5].y);
  hp[7] = make_float4(hB[6].x,hB[6].y,hB[7].x,hB[7].y);
  *(float2*)(sumdt + (size_t)blk*256 + d0) = make_float2(sA, sB);
}

// --- combine: one (b,d,n) scalar chain per thread; 512 blocks --------------
__global__ __launch_bounds__(256) void k_scan_comb(const float* __restrict__ Alog,
      const float* __restrict__ sumdt, float* __restrict__ hend, int nc){
  const int blk = blockIdx.x;
  const int b  = blk >> 4;
  const int dg = blk & 15;
  const int tid = threadIdx.x;
  const int dl = tid >> 4;
  const int n  = tid & 15;
  const int d  = dg*16 + dl;
  const float anl2 = -__expf(Alog[d*16 + n]) * 1.44269504f;
  float carry = 0.f;
  const size_t basei = (size_t)b*nc;
  for (int c=0;c<nc;c++){
    size_t blkc = basei + c;
    size_t hidx = (blkc*256 + d)*16 + n;
    float he  = hend[hidx];
    float sdt = sumdt[blkc*256 + d];
    hend[hidx] = carry;
    carry = fmaf(exp2f(sdt*anl2), carry, he);
  }
}

template<int CL>
__global__ __launch_bounds__(128) void k_scan_p2(const bf16* __restrict__ xcin,
      const bf16* __restrict__ dtb, const float* __restrict__ BC,
      const bf16* __restrict__ zg, const float* __restrict__ Alog,
      const float* __restrict__ Dpar, const float* __restrict__ hend,
      bf16* __restrict__ ym, int nc, int cl_rt){
  const int blk = blockIdx.x;
  const int b = blk / nc;
  const int c = blk - b*nc;
  const int d0 = threadIdx.x*2;
  const int cl = CL ? CL : cl_rt;
  f32x2 anlA[8], anlB[8];
  const bool okA = load_A(Alog, d0,   anlA);
  const bool okB = load_A(Alog, d0+1, anlB);
  float2 Dp2 = *(const float2*)(Dpar + d0);
  f32x2 hA[8], hB[8];
  {
    const float4* hp = (const float4*)(hend + ((size_t)blk*256 + d0)*16);
    float4 v0=hp[0], v1=hp[1], v2=hp[2], v3=hp[3];
    float4 v4=hp[4], v5=hp[5], v6=hp[6], v7=hp[7];
    hA[0].x=v0.x; hA[0].y=v0.y;  hA[1].x=v0.z; hA[1].y=v0.w;
    hA[2].x=v1.x; hA[2].y=v1.y;  hA[3].x=v1.z; hA[3].y=v1.w;
    hA[4].x=v2.x; hA[4].y=v2.y;  hA[5].x=v2.z; hA[5].y=v2.w;
    hA[6].x=v3.x; hA[6].y=v3.y;  hA[7].x=v3.z; hA[7].y=v3.w;
    hB[0].x=v4.x; hB[0].y=v4.y;  hB[1].x=v4.z; hB[1].y=v4.w;
    hB[2].x=v5.x; hB[2].y=v5.y;  hB[3].x=v5.z; hB[3].y=v5.w;
    hB[4].x=v6.x; hB[4].y=v6.y;  hB[5].x=v6.z; hB[5].y=v6.w;
    hB[6].x=v7.x; hB[6].y=v7.y;  hB[7].x=v7.z; hB[7].y=v7.w;
  }
  const size_t rowbase = (size_t)b*S_ + (size_t)c*cl;
  #pragma unroll 2
  for (int t=0;t<cl;t++){
    size_t row = rowbase + t;
    unsigned int dtp = *(const unsigned int*)(dtb  + row*256 + d0);
    unsigned int up  = *(const unsigned int*)(xcin + row*256 + d0);
    unsigned int gp  = *(const unsigned int*)(zg   + row*256 + d0);
    float dtA = uphalf((unsigned short)(dtp & 0xffffu));
    float dtB = uphalf((unsigned short)(dtp >> 16));
    float uA  = uphalf((unsigned short)(up  & 0xffffu));
    float uB  = uphalf((unsigned short)(up  >> 16));
    const float4* bp = (const float4*)(BC + row*32);
    float4 Bv[4] = {bp[0], bp[1], bp[2], bp[3]};
    float4 Cv[4] = {bp[4], bp[5], bp[6], bp[7]};
    f32x2 B2[8], C2[8];
    unpackBC(Bv, B2);
    unpackBC(Cv, C2);
    f32x2 duA; duA.x = dtA*uA; duA.y = dtA*uA;
    f32x2 duB; duB.x = dtB*uB; duB.y = dtB*uB;
    f32x2 dAA[8], dAB[8];
    comp_dA2(dAA, dtA, okA, anlA);
    comp_dA2(dAB, dtB, okB, anlB);
    f32x2 accA; accA.x=0.f; accA.y=0.f;
    f32x2 accB; accB.x=0.f; accB.y=0.f;
    #pragma unroll
    for (int i=0;i<8;i++){
      hA[i] = dAA[i]*hA[i] + duA*B2[i];
      hB[i] = dAB[i]*hB[i] + duB*B2[i];
      accA = accA + hA[i]*C2[i];
      accB = accB + hB[i]*C2[i];
    }
    float pA = accA.x + accA.y;
    float pB = accB.x + accB.y;
    float yA = fmaf(uA, Dp2.x, pA);
    float yB = fmaf(uB, Dp2.y, pB);
    float gA = uphalf((unsigned short)(gp & 0xffffu));   // silu pre-applied
    float gB = uphalf((unsigned short)(gp >> 16));
    *(unsigned int*)(ym + row*256 + d0) = pk2(yA*gA, yB*gB);
  }
}

// ------- gemm_out (MFMA): dx = ym @ W_out (K=256), fwd/bwd-fold ------------
__global__ __launch_bounds__(256) void k_gemm_out_mfma(const bf16* __restrict__ ym,
      const bf16* __restrict__ Wt, bf16* __restrict__ dx, int rev){
  __shared__ __align__(16) unsigned short a_sh[64][136];
  __shared__ __align__(16) unsigned short b_sh[64][136];
  const int blk = blockIdx.x;                // 1344 * 2
  const int bm = blk >> 1, bn = blk & 1;
  const int r0 = bm*64, n0 = bn*64;
  const int b  = r0 / S_;
  const int t0 = r0 - b*S_;
  const int tid = threadIdx.x;
  const int lane = tid & 63, wv = tid >> 6;
  const int wr = (wv>>1)*32, wc = (wv&1)*32;
  const int fr = lane & 15, fk = (lane>>4)*8;
  const f32x4 zero = {0.f,0.f,0.f,0.f};
  f32x4 acc[2][2] = {{zero,zero},{zero,zero}};

  for (int kst=0;kst<2;kst++){
    if (kst) __syncthreads();
    #pragma unroll
    for (int q=0;q<4;q++){
      int fid = tid + 256*q;
      int r = fid >> 4, g = fid & 15;
      *(uint4*)&a_sh[r][g*8] = *(const uint4*)(ym + (size_t)(r0+r)*256 + kst*128 + g*8);
      *(uint4*)&b_sh[r][g*8] = *(const uint4*)(Wt + (size_t)(n0+r)*256 + kst*128 + g*8);
    }
    __syncthreads();
    #pragma unroll
    for (int ks=0;ks<4;ks++){
      bf16x8 a0 = *(const bf16x8*)&a_sh[wr+fr   ][ks*32+fk];
      bf16x8 a1 = *(const bf16x8*)&a_sh[wr+16+fr][ks*32+fk];
      bf16x8 b0 = *(const bf16x8*)&b_sh[wc+fr   ][ks*32+fk];
      bf16x8 b1 = *(const bf16x8*)&b_sh[wc+16+fr][ks*32+fk];
      acc[0][0] = MFMA16(a0,b0,acc[0][0]);
      acc[0][1] = MFMA16(a0,b1,acc[0][1]);
      acc[1][0] = MFMA16(a1,b0,acc[1][0]);
      acc[1][1] = MFMA16(a1,b1,acc[1][1]);
    }
  }
  #pragma unroll
  for (int fi=0;fi<2;fi++){
    #pragma unroll
    for (int fj=0;fj<2;fj++){
      int c = n0 + wc + fj*16 + fr;
      #pragma unroll
      for (int r=0;r<4;r++){
        int t = t0 + wr + fi*16 + (lane>>4)*4 + r;
        size_t drow = (size_t)b*S_ + (rev ? (S_-1 - t) : t);
        if (rev){
          float old = bf2f(dx[drow*128 + c]);
          dx[drow*128 + c] = f2bf(old + 0.5f*acc[fi][fj][r]);
        } else {
          dx[drow*128 + c] = f2bf(0.5f*acc[fi][fj][r]);
        }
      }
    }
  }
}

// --- combine + layernorm + residual (vectorized: 4 ch/lane, 2 rows/wave) ---
__global__ __launch_bounds__(256) void k_combine_ln(const bf16* __restrict__ dx,
      const float* __restrict__ lnw, const float* __restrict__ lnb,
      float* __restrict__ x){
  const int tid  = threadIdx.x;
  const int wv   = tid >> 6;
  const int lane = tid & 63;
  const int row  = blockIdx.x*8 + wv*2 + (lane >> 5);
  const int c0   = (lane & 31)*4;
  ushort4 d4 = *(const ushort4*)(dx + (size_t)row*128 + c0);
  float v0 = uphalf(d4.x), v1 = uphalf(d4.y), v2 = uphalf(d4.z), v3 = uphalf(d4.w);
  float s = (v0+v1)+(v2+v3);
  #pragma unroll
  for (int m=1;m<32;m<<=1) s += __shfl_xor(s, m);
  float mu = s * (1.f/128.f);
  float e0 = v0-mu, e1 = v1-mu, e2 = v2-mu, e3 = v3-mu;
  float q = (e0*e0+e1*e1)+(e2*e2+e3*e3);
  #pragma unroll
  for (int m=1;m<32;m<<=1) q += __shfl_xor(q, m);
  float rs = rsqrtf(q*(1.f/128.f) + 1e-5f);
  float4 w4 = *(const float4*)(lnw + c0);
  float4 b4 = *(const float4*)(lnb + c0);
  float4 xv = *(float4*)(x + (size_t)row*128 + c0);
  xv.x += e0*rs*w4.x + b4.x;
  xv.y += e1*rs*w4.y + b4.y;
  xv.z += e2*rs*w4.z + b4.z;
  xv.w += e3*rs*w4.w + b4.w;
  *(float4*)(x + (size_t)row*128 + c0) = xv;
}

// ---------------- pyramid gather ----------------
__global__ void k_pyramid(const float* __restrict__ x, float* __restrict__ out){
  int idx = blockIdx.x*256 + threadIdx.x;
  int j = idx & 31;
  int i = (idx >> 5) & 31;
  int c = (idx >> 10) & 127;
  int m = (idx >> 17) & 31;
  int o = idx >> 22;
  int base = o*1344;
  size_t xm = ((size_t)m * S_ + base) * 128 + c;
  float v = x[xm + (size_t)(320 + i*32 + j)*128]
          + x[xm + (size_t)(64 + (i>>1)*16 + (j>>1))*128]
          + x[xm + (size_t)((i>>2)*8 + (j>>2))*128];
  out[idx] = v;
}

extern "C" void kernel_launch(void* const* d_in, const int* in_sizes, int n_in,
                              void* d_out, int out_size, void* d_ws, size_t ws_size,
                              hipStream_t stream){
  const float* f0   = (const float*)d_in[0];
  const float* f1   = (const float*)d_in[1];
  const float* W_in = (const float*)d_in[2];
  const float* cw   = (const float*)d_in[3];
  const float* cb   = (const float*)d_in[4];
  const float* Wx   = (const float*)d_in[5];
  const float* Wdt  = (const float*)d_in[6];
  const float* bdt  = (const float*)d_in[7];
  const float* Alog = (const float*)d_in[8];
  const float* Dpar = (const float*)d_in[9];
  const float* Wout = (const float*)d_in[10];
  const float* lnw  = (const float*)d_in[11];
  const float* lnb  = (const float*)d_in[12];

  const size_t base = 214695936;
  int nc = 0;
  const int cand[6] = {84,42,21,12,6,2};
  for (int i=0;i<6;i++){
    size_t need = base + (size_t)32*cand[i]*256*16*4;
    if (ws_size >= need){ nc = cand[i]; break; }
  }
  if (nc == 0) return;
  const int cl = S_/nc;

  char* ws = (char*)d_ws;
  float* x      = (float*)(ws + 0);
  bf16*  xi     = (bf16*) (ws + 44040192);
  bf16*  dtb    = (bf16*) (ws + 44040192);
  bf16*  z      = (bf16*) (ws + 88080384);
  bf16*  xc     = (bf16*) (ws + 132120576);
  float* BC     = (float*)(ws + 176160768);
  float* sumdt  = (float*)(ws + 187170816);
  bf16*  Wt_in  = (bf16*) (ws + 189923328);
  bf16*  Wt_out = (bf16*) (ws + 190447616);
  bf16*  Wxt    = (bf16*) (ws + 190709760);
  bf16*  dx     = (bf16*) (ws + 192675840);
  float* hend   = (float*)(ws + 214695936);

  k_init_x<<<43008,256,0,stream>>>(f0, f1, x);
  k_wconv <<<1728,256,0,stream>>>(W_in, Wx, Wout, Wt_in, Wxt, Wt_out);

  for (int l=0;l<2;l++){
    for (int r=0;r<2;r++){
      int lr = l*2 + r;
      const float* Al = Alog + (size_t)lr*256*16;
      k_gemm_in_mfma<<<1344,256,0,stream>>>(x, Wt_in + (size_t)lr*65536, xi, z, r);
      k_conv_silu   <<<2688,256,0,stream>>>(xi, cw + lr*256*4, cb + lr*256, xc);
      if (nc == 84){
        k_gemm_x_dt_scan<<<1344,256,0,stream>>>(xc, Wxt + (size_t)lr*12288,
                                                Wdt + (size_t)lr*8*256, bdt + lr*256,
                                                BC, dtb, Al, hend, sumdt);
      } else {
        k_gemm_x_dt_mfma<<<1344,256,0,stream>>>(xc, Wxt + (size_t)lr*12288,
                                                Wdt + (size_t)lr*8*256, bdt + lr*256, BC, dtb);
        k_scan_p1<<<32*nc,128,0,stream>>>(xc, dtb, BC, Al, hend, sumdt, nc, cl);
      }
      k_scan_comb<<<512,256,0,stream>>>(Al, sumdt, hend, nc);
      if (cl == 32)
        k_scan_p2<32><<<32*nc,128,0,stream>>>(xc, dtb, BC, z, Al, Dpar + lr*256,
                                              hend, xc, nc, cl);
      else if (cl == 64)
        k_scan_p2<64><<<32*nc,128,0,stream>>>(xc, dtb, BC, z, Al, Dpar + lr*256,
                                              hend, xc, nc, cl);
      else
        k_scan_p2<0> <<<32*nc,128,0,stream>>>(xc, dtb, BC, z, Al, Dpar + lr*256,
                                              hend, xc, nc, cl);
      k_gemm_out_mfma<<<2688,256,0,stream>>>(xc, Wt_out + (size_t)lr*32768, dx, r);
    }
    k_combine_ln<<<10752,256,0,stream>>>(dx, lnw + l*128, lnb + l*128, x);
  }

  k_pyramid<<<32768,256,0,stream>>>(x, (float*)d_out);
}